// Round 14
// baseline (1196.704 us; speedup 1.0000x reference)
//
#include <hip/hip_runtime.h>
#include <math.h>

#define Bn 16
#define Cn 256
#define Hn 96
#define Wn 96
#define Nn 9216
#define PIXn 147456
#define XSZk ((size_t)Bn*Cn*Nn)
#define YSZk ((size_t)Bn*64*Nn)
#define ATTSZ ((size_t)PIXn*96)

typedef short bf8 __attribute__((ext_vector_type(8)));
typedef float f32x4 __attribute__((ext_vector_type(4)));
#define MFMA(a,b,c) __builtin_amdgcn_mfma_f32_16x16x32_bf16(a,b,c,0,0,0)

typedef unsigned short ushort_t;
typedef _Float16 h16;

__device__ inline ushort_t f2bf(float f){
  union{float f; unsigned int u;} v; v.f=f;
  unsigned int r = v.u + 0x7fffu + ((v.u>>16)&1u);
  return (ushort_t)(r>>16);
}
__device__ inline float bf2f(ushort_t s){
  union{unsigned int u; float f;} v; v.u = ((unsigned int)s)<<16;
  return v.f;
}
__device__ inline ushort_t f2h(float f){
  union{h16 h; ushort_t u;} v; v.h=(h16)f; return v.u;
}
__device__ inline float h2f(ushort_t u){
  union{ushort_t u; h16 h;} v; v.u=u; return (float)v.h;
}

__device__ inline float waveSum(float v){
#pragma unroll
  for(int o=32;o;o>>=1) v += __shfl_down(v,o,64);
  return v;
}
__device__ inline float waveMax(float v){
#pragma unroll
  for(int o=32;o;o>>=1) v = fmaxf(v,__shfl_down(v,o,64));
  return v;
}

// ---------------- gating ----------------

template<int XBW>
__global__ __launch_bounds__(1024) void k_pass1(const float* __restrict__ x,
    const float* __restrict__ wqr, float* __restrict__ xmean,
    float* __restrict__ partp, ushort_t* __restrict__ XB){
  int cg = blockIdx.x, b = blockIdx.y, tid = threadIdx.x;
  __shared__ float r16[16];
  float mp[2][8];
#pragma unroll
  for(int u=0;u<2;u++)
#pragma unroll
    for(int e=0;e<8;e++) mp[u][e]=0.f;
  for(int cc=0;cc<16;cc++){
    int c = cg*16+cc;
    const float* row = x + ((size_t)b*Cn + c)*Nn;
    float w = wqr[c];
    float s = 0.f;
#pragma unroll
    for(int u=0;u<2;u++){
      int ch = tid + u*1024;
      if(ch < 1152){
        float4 a = *(const float4*)&row[ch*8];
        float4 d = *(const float4*)&row[ch*8+4];
        float v0=a.x,v1=a.y,v2=a.z,v3=a.w,v4=d.x,v5=d.y,v6=d.z,v7=d.w;
        s += ((v0+v1)+(v2+v3))+((v4+v5)+(v6+v7));
        mp[u][0]+=w*v0; mp[u][1]+=w*v1; mp[u][2]+=w*v2; mp[u][3]+=w*v3;
        mp[u][4]+=w*v4; mp[u][5]+=w*v5; mp[u][6]+=w*v6; mp[u][7]+=w*v7;
        if(XBW){
          uint4 pk;
          pk.x=(unsigned)f2bf(v0)|((unsigned)f2bf(v1)<<16);
          pk.y=(unsigned)f2bf(v2)|((unsigned)f2bf(v3)<<16);
          pk.z=(unsigned)f2bf(v4)|((unsigned)f2bf(v5)<<16);
          pk.w=(unsigned)f2bf(v6)|((unsigned)f2bf(v7)<<16);
          *(uint4*)&XB[((size_t)b*Cn + c)*Nn + ch*8] = pk;
        }
      }
    }
    s = waveSum(s);
    if((tid&63)==0) r16[tid>>6]=s;
    __syncthreads();
    if(tid==0){
      float t=0.f;
      for(int i=0;i<16;i++) t+=r16[i];
      xmean[(size_t)b*Cn + c] = t*(1.f/Nn);
    }
    __syncthreads();
  }
  float* dst = partp + ((size_t)cg*Bn + b)*Nn;
#pragma unroll
  for(int u=0;u<2;u++){
    int ch = tid + u*1024;
    if(ch < 1152){
      float4 o1, o2;
      o1.x=mp[u][0]; o1.y=mp[u][1]; o1.z=mp[u][2]; o1.w=mp[u][3];
      o2.x=mp[u][4]; o2.y=mp[u][5]; o2.z=mp[u][6]; o2.w=mp[u][7];
      *(float4*)&dst[ch*8]   = o1;
      *(float4*)&dst[ch*8+4] = o2;
    }
  }
}

template<int XBR>
__global__ __launch_bounds__(1024) void k_pass2(const float* __restrict__ x,
    const ushort_t* __restrict__ XB, const float* __restrict__ wvec,
    const float* __restrict__ maskb, float* __restrict__ xw,
    float* __restrict__ partp){
  int cg = blockIdx.x, b = blockIdx.y, tid = threadIdx.x;
  __shared__ float r16[16];
  float cp[2][8], mk[2][8];
#pragma unroll
  for(int u=0;u<2;u++){
    int ch = tid + u*1024;
    if(ch < 1152){
      float4 a = *(const float4*)&maskb[(size_t)b*Nn + ch*8];
      float4 d = *(const float4*)&maskb[(size_t)b*Nn + ch*8 + 4];
      mk[u][0]=a.x; mk[u][1]=a.y; mk[u][2]=a.z; mk[u][3]=a.w;
      mk[u][4]=d.x; mk[u][5]=d.y; mk[u][6]=d.z; mk[u][7]=d.w;
    }
#pragma unroll
    for(int e=0;e<8;e++) cp[u][e]=0.f;
  }
  for(int cc=0;cc<16;cc++){
    int c = cg*16+cc;
    float w = wvec[(size_t)b*Cn + c];
    float s = 0.f;
#pragma unroll
    for(int u=0;u<2;u++){
      int ch = tid + u*1024;
      if(ch < 1152){
        float v[8];
        if(XBR){
          uint4 q = *(const uint4*)&XB[((size_t)b*Cn + c)*Nn + ch*8];
          unsigned* qp=(unsigned*)&q;
#pragma unroll
          for(int k=0;k<4;k++){
            v[2*k]   = bf2f((ushort_t)(qp[k]&0xffff));
            v[2*k+1] = bf2f((ushort_t)(qp[k]>>16));
          }
        } else {
          const float* row = x + ((size_t)b*Cn + c)*Nn;
          float4 a = *(const float4*)&row[ch*8];
          float4 d = *(const float4*)&row[ch*8+4];
          v[0]=a.x; v[1]=a.y; v[2]=a.z; v[3]=a.w;
          v[4]=d.x; v[5]=d.y; v[6]=d.z; v[7]=d.w;
        }
#pragma unroll
        for(int e=0;e<8;e++){
          s += mk[u][e]*v[e];
          cp[u][e] += w*v[e];
        }
      }
    }
    s = waveSum(s);
    if((tid&63)==0) r16[tid>>6]=s;
    __syncthreads();
    if(tid==0){
      float t=0.f;
      for(int i=0;i<16;i++) t+=r16[i];
      xw[(size_t)b*Cn + c] = t;
    }
    __syncthreads();
  }
  float* dst = partp + ((size_t)cg*Bn + b)*Nn;
#pragma unroll
  for(int u=0;u<2;u++){
    int ch = tid + u*1024;
    if(ch < 1152){
      float4 o1, o2;
      o1.x=cp[u][0]; o1.y=cp[u][1]; o1.z=cp[u][2]; o1.w=cp[u][3];
      o2.x=cp[u][4]; o2.y=cp[u][5]; o2.z=cp[u][6]; o2.w=cp[u][7];
      *(float4*)&dst[ch*8]   = o1;
      *(float4*)&dst[ch*8+4] = o2;
    }
  }
}

__global__ void k_red16(const float* __restrict__ part, float* __restrict__ out){
  size_t p = (size_t)blockIdx.x*256 + threadIdx.x;
  float s=0.f;
#pragma unroll
  for(int cg=0;cg<16;cg++) s += part[(size_t)cg*Bn*Nn + p];
  out[p]=s;
}

__device__ inline void softmax_n_body(const float* __restrict__ in,
    float* __restrict__ out, int b, int mode){
  int tid=threadIdx.x, lane=tid&63, wid=tid>>6;
  const float* p = in + (size_t)b*Nn;
  __shared__ float red[16];
  __shared__ float bc2[2];
  float mx=-3e38f;
  for(int i=tid;i<Nn;i+=1024) mx=fmaxf(mx,p[i]);
  mx = waveMax(mx);
  if(lane==0) red[wid]=mx;
  __syncthreads();
  if(tid==0){ float m=red[0]; for(int i=1;i<16;i++) m=fmaxf(m,red[i]); bc2[0]=m; }
  __syncthreads();
  mx=bc2[0];
  float s=0.f;
  for(int i=tid;i<Nn;i+=1024) s+=expf(p[i]-mx);
  s = waveSum(s);
  __syncthreads();
  if(lane==0) red[wid]=s;
  __syncthreads();
  if(tid==0){ float t=0.f; for(int i=0;i<16;i++) t+=red[i]; bc2[1]=t; }
  __syncthreads();
  float inv=1.f/bc2[1];
  for(int i=tid;i<Nn;i+=1024){
    float e=expf(p[i]-mx)*inv;
    out[(size_t)b*Nn+i] = mode ? 1.f/(1.f+expf(-e)) : e;
  }
}

__global__ __launch_bounds__(1024) void k_sn1(const float* __restrict__ mraw,
    float* __restrict__ maskb, const float* __restrict__ xmean,
    const float* __restrict__ wql, const float* __restrict__ wvl,
    float* __restrict__ wvec){
  if(blockIdx.x < 16){
    softmax_n_body(mraw, maskb, blockIdx.x, 0);
  } else {
    int b = blockIdx.x - 16, t = threadIdx.x;
    __shared__ float xm[Cn];
    __shared__ float av[128];
    if(t<Cn) xm[t] = xmean[b*Cn+t];
    __syncthreads();
    if(t<128){
      float s=0.f;
      for(int c=0;c<Cn;c++) s += wql[t*Cn+c]*xm[c];
      av[t]=s;
    }
    __syncthreads();
    if(t<Cn){
      float s=0.f;
      for(int m=0;m<128;m++) s += av[m]*wvl[m*Cn+t];
      wvec[b*Cn+t]=s;
    }
  }
}

__global__ __launch_bounds__(1024) void k_sn2(const float* __restrict__ craw,
    float* __restrict__ m2, const float* __restrict__ xw,
    const float* __restrict__ wvr, const float* __restrict__ wup,
    const float* __restrict__ bup, float* __restrict__ g1){
  if(blockIdx.x < 16){
    softmax_n_body(craw, m2, blockIdx.x, 1);
  } else {
    int b = blockIdx.x - 16, t = threadIdx.x;
    __shared__ float xs[Cn];
    __shared__ float cx[128];
    if(t<Cn) xs[t]=xw[b*Cn+t];
    __syncthreads();
    if(t<128){
      float s=0.f;
      for(int c=0;c<Cn;c++) s += wvr[t*Cn+c]*xs[c];
      cx[t]=s;
    }
    __syncthreads();
    if(t<Cn){
      float s=bup[t];
      for(int m=0;m<128;m++) s += wup[t*128+m]*cx[m];
      g1[b*Cn+t]=1.f/(1.f+expf(-s));
    }
  }
}

// ---------------- cross-attention, MFMA ----------------

__global__ void k_packb(const float* __restrict__ wq, const float* __restrict__ bq,
                        const float* __restrict__ wk, const float* __restrict__ bk,
                        const float* __restrict__ wv, const float* __restrict__ bv,
                        ushort_t* __restrict__ Wp, float* __restrict__ bp){
  int o = blockIdx.x, t = threadIdx.x;
  const float* src; float bs;
  if(o<32){ src = wq + o*Cn; bs = bq[o]; }
  else if(o<64){ src = wk + (o-32)*Cn; bs = bk[o-32]; }
  else { src = wv + (o-64)*Cn; bs = bv[o-64]; }
  Wp[o*Cn+t] = f2bf(src[t]);
  if(t==0) bp[o] = bs;
}

#define AP 40
#define BP 264
#define GP 68

// fused QKV GEMM, NT=64 (round-11 config)
template<int GATED, int XBR>
__global__ __launch_bounds__(256) void k_gemm_qkv(
    const ushort_t* __restrict__ tb, const float* __restrict__ x,
    const ushort_t* __restrict__ XBp,
    const float* __restrict__ g1, const float* __restrict__ m2,
    const ushort_t* __restrict__ Wp, const float* __restrict__ bp,
    ushort_t* __restrict__ Yqk, ushort_t* __restrict__ Vb, int sel){
  __shared__ ushort_t SM[320*AP + 64*BP];
  __shared__ float gsh[256];
  ushort_t* Ws = SM;
  ushort_t* Bt = SM + 320*AP;
  int b = blockIdx.y;
  int n0 = blockIdx.x*64;
  int tid = threadIdx.x, lane = tid&63, wid = tid>>6;

  if(GATED){
    gsh[tid] = g1[b*Cn + tid];
    __syncthreads();
    float scl_n = (sel==1) ? m2[(size_t)b*Nn + n0 + (tid&63)] : 0.f;
    int cg = (tid>>6)*8;
#pragma unroll
    for(int p=0;p<8;p++){
      int c8 = p*32 + cg;
      float fv[8];
      if(XBR){
        const ushort_t* xb = XBp + (size_t)b*Cn*Nn + n0 + (tid&63);
#pragma unroll
        for(int k2=0;k2<8;k2++){
          float xf = bf2f(xb[(size_t)(c8+k2)*Nn]);
          fv[k2] = xf * (sel==0 ? gsh[c8+k2] : scl_n);
        }
      } else {
        const float* xb = x + (size_t)b*Cn*Nn + n0 + (tid&63);
#pragma unroll
        for(int k2=0;k2<8;k2++){
          float xf = xb[(size_t)(c8+k2)*Nn];
          fv[k2] = xf * (sel==0 ? gsh[c8+k2] : scl_n);
        }
      }
      uint4 pk;
      pk.x = (unsigned)f2bf(fv[0]) | ((unsigned)f2bf(fv[1])<<16);
      pk.y = (unsigned)f2bf(fv[2]) | ((unsigned)f2bf(fv[3])<<16);
      pk.z = (unsigned)f2bf(fv[4]) | ((unsigned)f2bf(fv[5])<<16);
      pk.w = (unsigned)f2bf(fv[6]) | ((unsigned)f2bf(fv[7])<<16);
      *(uint4*)&Bt[(tid&63)*BP + c8] = pk;
    }
  } else {
    const ushort_t* xb = tb + (size_t)b*Cn*Nn + n0 + (tid&63);
    int cg = (tid>>6)*8;
#pragma unroll
    for(int p=0;p<8;p++){
      int c8 = p*32 + cg;
      unsigned e0=xb[(size_t)(c8+0)*Nn], e1=xb[(size_t)(c8+1)*Nn];
      unsigned e2=xb[(size_t)(c8+2)*Nn], e3=xb[(size_t)(c8+3)*Nn];
      unsigned e4=xb[(size_t)(c8+4)*Nn], e5=xb[(size_t)(c8+5)*Nn];
      unsigned e6=xb[(size_t)(c8+6)*Nn], e7=xb[(size_t)(c8+7)*Nn];
      uint4 pk;
      pk.x = e0 | (e1<<16); pk.y = e2 | (e3<<16);
      pk.z = e4 | (e5<<16); pk.w = e6 | (e7<<16);
      *(uint4*)&Bt[(tid&63)*BP + c8] = pk;
    }
  }

  f32x4 acc[5][4];
#pragma unroll
  for(int f=0;f<5;f++)
#pragma unroll
    for(int g=0;g<4;g++) acc[f][g] = (f32x4){0.f,0.f,0.f,0.f};

  for(int ki=0;ki<8;ki++){
    __syncthreads();
#pragma unroll
    for(int q=0;q<5;q++){
      int fidx = q*256 + tid;
      int o = fidx>>2, kk = (fidx&3)*8;
      uint4 wv = *(const uint4*)&Wp[o*Cn + ki*32 + kk];
      *(uint4*)&Ws[o*AP + kk] = wv;
    }
    __syncthreads();
    bf8 bfr[4];
#pragma unroll
    for(int g=0;g<4;g++)
      bfr[g] = *(const bf8*)&Bt[(g*16 + (lane&15))*BP + ki*32 + (lane>>4)*8];
#pragma unroll
    for(int f=0;f<5;f++){
      bf8 a = *(const bf8*)&Ws[(wid*80 + f*16 + (lane&15))*AP + (lane>>4)*8];
#pragma unroll
      for(int g=0;g<4;g++) acc[f][g] = MFMA(a, bfr[g], acc[f][g]);
    }
  }

  __syncthreads();
#pragma unroll
  for(int f=0;f<5;f++){
    int o = wid*80 + f*16 + (lane>>4)*4;
#pragma unroll
    for(int i=0;i<4;i++){
      float bias = bp[o+i];
#pragma unroll
      for(int g=0;g<4;g++)
        SM[(o+i)*GP + g*16 + (lane&15)] = f2bf(acc[f][g][i] + bias);
    }
  }
  __syncthreads();
  for(int u=tid; u<320*8; u+=256){
    int lo_ = u>>3, c8 = (u&7)*8;
    ushort_t* dst = (lo_<64) ? (Yqk + ((size_t)b*64 + lo_)*Nn)
                             : (Vb + ((size_t)b*Cn + (lo_-64))*Nn);
    *(uint4*)&dst[n0 + c8] = *(uint4*)&SM[lo_*GP + c8];
  }
}

// fused plane transpose: blocks [0, nY) transpose Y planes; [nY, nY+nV) V planes
__global__ __launch_bounds__(256) void k_tr2(const ushort_t* __restrict__ Ysrc,
    ushort_t* __restrict__ Ydst, const ushort_t* __restrict__ Vsrc,
    ushort_t* __restrict__ Vdst){
  __shared__ ushort_t Ls[96*98];
  int idx = blockIdx.x;
  const int nY = Bn*64;
  const ushort_t* src; ushort_t* dst;
  if(idx < nY){ src = Ysrc + (size_t)idx*Nn; dst = Ydst + (size_t)idx*Nn; }
  else { src = Vsrc + (size_t)(idx-nY)*Nn; dst = Vdst + (size_t)(idx-nY)*Nn; }
  int tid = threadIdx.x;
  for(int e=tid*2; e<Nn; e+=512){
    unsigned int u = *(const unsigned int*)&src[e];
    int r=e/96, c=e%96;
    *(unsigned int*)&Ls[r*98+c] = u;
  }
  __syncthreads();
  for(int e=tid*2; e<Nn; e+=512){
    int r=e/96, c=e%96;
    unsigned int u = (unsigned int)Ls[c*98+r] | (((unsigned int)Ls[(c+1)*98+r])<<16);
    *(unsigned int*)&dst[e] = u;
  }
}

// unified QK^T -> fp16 logits
__global__ __launch_bounds__(256) void k_e2(const ushort_t* __restrict__ Yqk,
    const ushort_t* __restrict__ Yqkt, ushort_t* __restrict__ attl,
    ushort_t* __restrict__ attr){
  __shared__ ushort_t Qt[96*AP];
  __shared__ ushort_t Kt[96*AP];
  int r = blockIdx.x, mode = blockIdx.y, b = blockIdx.z;
  const ushort_t* Y = mode ? Yqk : Yqkt;
  int pm   = mode ? 1  : 96;
  int pr   = mode ? 96 : 1;
  ushort_t* attx = mode ? attr : attl;
  int tid = threadIdx.x, lane = tid&63, wid = tid>>6;
  {
    int half = tid>>7;
    int cg   = (tid>>5)&3;
    int l32  = tid&31;
    ushort_t* T = half ? Kt : Qt;
    const ushort_t* S = Y + ((size_t)b*64 + half*32 + cg*8)*Nn + (size_t)r*96;
#pragma unroll
    for(int p=0;p<3;p++){
      int sp = p*32 + l32;
      unsigned e0=S[(size_t)0*Nn+sp], e1=S[(size_t)1*Nn+sp];
      unsigned e2=S[(size_t)2*Nn+sp], e3=S[(size_t)3*Nn+sp];
      unsigned e4=S[(size_t)4*Nn+sp], e5=S[(size_t)5*Nn+sp];
      unsigned e6=S[(size_t)6*Nn+sp], e7=S[(size_t)7*Nn+sp];
      uint4 pk;
      pk.x = e0 | (e1<<16); pk.y = e2 | (e3<<16);
      pk.z = e4 | (e5<<16); pk.w = e6 | (e7<<16);
      *(uint4*)&T[sp*AP + cg*8] = pk;
    }
  }
  __syncthreads();
  int mb = (wid>>1)*48, nb = (wid&1)*48;
  const f32x4 z4 = {0.f,0.f,0.f,0.f};
  f32x4 acc[3][3];
  bf8 a[3], bb[3];
#pragma unroll
  for(int f=0;f<3;f++) a[f] = *(const bf8*)&Qt[(mb+f*16+(lane&15))*AP + (lane>>4)*8];
#pragma unroll
  for(int g=0;g<3;g++) bb[g] = *(const bf8*)&Kt[(nb+g*16+(lane&15))*AP + (lane>>4)*8];
#pragma unroll
  for(int f=0;f<3;f++)
#pragma unroll
    for(int g=0;g<3;g++) acc[f][g] = MFMA(a[f], bb[g], z4);
#pragma unroll
  for(int f=0;f<3;f++)
#pragma unroll
    for(int i=0;i<4;i++){
      int m = mb + f*16 + (lane>>4)*4 + i;
      ushort_t* arow = attx + ((size_t)b*Nn + (size_t)m*pm + (size_t)r*pr)*96;
#pragma unroll
      for(int g=0;g<3;g++){
        int n = nb + g*16 + (lane&15);
        arow[n] = f2h(acc[f][g][i]);
      }
    }
}

#define SP 104   // att staging pitch (2-way only, free)
#define RP 100   // repack pitch (64-row buffer)

// unified PV with FUSED softmax, 256 thr, 128 ch/block: blockIdx.y = mode*2+half
// Reads raw fp16 logits (attl,attr); computes per-row softmax over 192 (diag mask
// on the attl half) and stages the needed bf16 half in LDS. MFMA+epilogue = round-11.
template<int RES, int XBR>
__global__ __launch_bounds__(256) void k_pv2(const ushort_t* __restrict__ VB,
    const ushort_t* __restrict__ VTb, const ushort_t* __restrict__ attl,
    const ushort_t* __restrict__ attr, const float* __restrict__ x,
    const ushort_t* __restrict__ XBp,
    const float* __restrict__ g1, const float* __restrict__ m2,
    const ushort_t* __restrict__ residb, ushort_t* __restrict__ Tob,
    ushort_t* __restrict__ OTb, const float* __restrict__ gp, int sel){
  __shared__ ushort_t SMEM[96*SP];    // 19968B; repack 64*RP fits
  int r = blockIdx.x, mode = blockIdx.y>>1, half = blockIdx.y&1, b = blockIdx.z;
  float gm = gp[0];
  int tid = threadIdx.x, lane = tid&63, wid = tid>>6;
  const ushort_t* V = mode ? VTb : VB;
  size_t vbase = (size_t)b*Cn*Nn + (size_t)r*96;
  // prefetch V fragments (round-11 style: before staging, hides HBM latency)
  bf8 vf[6];
#pragma unroll
  for(int f=0;f<2;f++)
#pragma unroll
    for(int j=0;j<3;j++)
      vf[f*3+j] = *(const bf8*)&V[vbase
        + (size_t)(half*128 + wid*32 + f*16 + (lane&15))*Nn + j*32 + (lane>>4)*8];
  // fused softmax staging: 8 half-waves, each owns one row per pass
  {
    int hw = tid>>5, l32 = tid&31;
#pragma unroll
    for(int pass=0; pass<12; pass++){
      int n = pass*8 + hw;
      size_t p = (size_t)b*Nn + (mode ? (size_t)n*96 + r : (size_t)r*96 + n);
      int mel = mode ? n : r;
      const ushort_t* al = attl + p*96;
      const ushort_t* ar = attr + p*96;
      float vl[3], vr[3];
#pragma unroll
      for(int k=0;k<3;k++){
        int el = l32 + 32*k;
        float t = h2f(al[el]);
        vl[k] = (el==mel) ? -1e30f : t;
        vr[k] = h2f(ar[el]);
      }
      float mx = fmaxf(fmaxf(fmaxf(vl[0],vl[1]),fmaxf(vl[2],vr[0])),fmaxf(vr[1],vr[2]));
#pragma unroll
      for(int o=16;o;o>>=1) mx = fmaxf(mx, __shfl_xor(mx, o, 32));
      float s = 0.f;
      float e[6];
      e[0]=expf(vl[0]-mx); e[1]=expf(vl[1]-mx); e[2]=expf(vl[2]-mx);
      e[3]=expf(vr[0]-mx); e[4]=expf(vr[1]-mx); e[5]=expf(vr[2]-mx);
      s = ((e[0]+e[1])+(e[2]+e[3]))+(e[4]+e[5]);
#pragma unroll
      for(int o=16;o;o>>=1) s += __shfl_xor(s, o, 32);
      float inv = 1.f/s;
#pragma unroll
      for(int k=0;k<3;k++){
        float val = (mode ? e[k] : e[3+k]) * inv;
        SMEM[n*SP + l32 + 32*k] = f2bf(val);
      }
    }
  }
  __syncthreads();
  f32x4 acc[2][6];
#pragma unroll
  for(int f=0;f<2;f++)
#pragma unroll
    for(int g=0;g<6;g++) acc[f][g] = (f32x4){0.f,0.f,0.f,0.f};
#pragma unroll
  for(int j0=0;j0<3;j0++){
    bf8 bfr[6];
#pragma unroll
    for(int g=0;g<6;g++)
      bfr[g] = *(const bf8*)&SMEM[(g*16+(lane&15))*SP + j0*32 + (lane>>4)*8];
#pragma unroll
    for(int f=0;f<2;f++)
#pragma unroll
      for(int g=0;g<6;g++) acc[f][g] = MFMA(vf[f*3+j0], bfr[g], acc[f][g]);
  }
  // epilogue: two f-phases, all 4 waves active; 64-row repack buffer
#pragma unroll
  for(int ph=0; ph<2; ph++){
    __syncthreads();
    {
      int f = ph;
      int rl = wid*16 + (lane>>4)*4;           // local row base 0..63
#pragma unroll
      for(int i=0;i<4;i++)
#pragma unroll
        for(int g=0;g<6;g++)
          SMEM[(rl+i)*RP + g*16 + (lane&15)] = f2bf(gm*acc[f][g][i]);
    }
    __syncthreads();
    for(int u=tid; u<64*12; u+=256){
      int rl = u/12, q8 = (u%12)*8;
      int c = half*128 + (rl>>4)*32 + ph*16 + (rl&15);
      size_t row = vbase + (size_t)c*Nn;
      uint4 v = *(uint4*)&SMEM[rl*RP + q8];
      if(mode){
        *(uint4*)&OTb[row + q8] = v;
      } else {
        unsigned* vp=(unsigned*)&v;
        float rs[8];
        if(RES==1){
          uint4 rv = *(const uint4*)&residb[row + q8];
          unsigned* rp=(unsigned*)&rv;
#pragma unroll
          for(int k=0;k<4;k++){
            rs[2*k]   = bf2f((ushort_t)(rp[k]&0xffff));
            rs[2*k+1] = bf2f((ushort_t)(rp[k]>>16));
          }
        } else {
          float xv[8];
          if(XBR){
            uint4 xq = *(const uint4*)&XBp[row + q8];
            unsigned* xp=(unsigned*)&xq;
#pragma unroll
            for(int k=0;k<4;k++){
              xv[2*k]   = bf2f((ushort_t)(xp[k]&0xffff));
              xv[2*k+1] = bf2f((ushort_t)(xp[k]>>16));
            }
          } else {
            float4 x1 = *(const float4*)&x[row + q8];
            float4 x2 = *(const float4*)&x[row + q8 + 4];
            xv[0]=x1.x; xv[1]=x1.y; xv[2]=x1.z; xv[3]=x1.w;
            xv[4]=x2.x; xv[5]=x2.y; xv[6]=x2.z; xv[7]=x2.w;
          }
          if(sel==0){
            float g = g1[b*Cn + c];
#pragma unroll
            for(int k=0;k<8;k++) rs[k] = xv[k]*g;
          } else {
            float4 m1 = *(const float4*)&m2[(size_t)b*Nn + (size_t)r*96 + q8];
            float4 m2v= *(const float4*)&m2[(size_t)b*Nn + (size_t)r*96 + q8 + 4];
            float mv[8] = {m1.x,m1.y,m1.z,m1.w,m2v.x,m2v.y,m2v.z,m2v.w};
#pragma unroll
            for(int k=0;k<8;k++) rs[k] = xv[k]*mv[k];
          }
        }
        uint4 o; unsigned* op=(unsigned*)&o;
#pragma unroll
        for(int k=0;k<4;k++){
          float lo = bf2f((ushort_t)(vp[k]&0xffff)) + rs[2*k];
          float hi = bf2f((ushort_t)(vp[k]>>16))    + rs[2*k+1];
          op[k] = (unsigned)f2bf(lo) | ((unsigned)f2bf(hi)<<16);
        }
        *(uint4*)&Tob[row + q8] = o;
      }
    }
  }
}

// merge: VAR 0: outb += OT^T ; VAR 2: outb += add + OT^T ; VAR 4: outf = add + OT^T
template<int VAR>
__global__ __launch_bounds__(256) void k_merge(float* __restrict__ outf,
    ushort_t* __restrict__ outb, const ushort_t* __restrict__ add,
    const ushort_t* __restrict__ OT){
  __shared__ ushort_t Ls[96*98];
  size_t base = (size_t)blockIdx.x * Nn;
  int tid = threadIdx.x;
  for(int e=tid*2; e<Nn; e+=512){
    int r=e/96, c=e%96;
    *(unsigned int*)&Ls[r*98+c] = *(const unsigned int*)&OT[base+e];
  }
  __syncthreads();
  for(int e=tid*4; e<Nn; e+=1024){
    int r=e/96, c=e%96;
    float t0 = bf2f(Ls[(c+0)*98+r]), t1 = bf2f(Ls[(c+1)*98+r]);
    float t2 = bf2f(Ls[(c+2)*98+r]), t3 = bf2f(Ls[(c+3)*98+r]);
    if(VAR==4){
      uint2 v = *(const uint2*)&add[base+e];
      float4 o;
      o.x = bf2f((ushort_t)(v.x&0xffff)) + t0;
      o.y = bf2f((ushort_t)(v.x>>16))    + t1;
      o.z = bf2f((ushort_t)(v.y&0xffff)) + t2;
      o.w = bf2f((ushort_t)(v.y>>16))    + t3;
      *(float4*)&outf[base+e] = o;
    } else {
      uint2 u = *(uint2*)&outb[base+e];
      float a0 = bf2f((ushort_t)(u.x&0xffff)) + t0;
      float a1 = bf2f((ushort_t)(u.x>>16))    + t1;
      float a2 = bf2f((ushort_t)(u.y&0xffff)) + t2;
      float a3 = bf2f((ushort_t)(u.y>>16))    + t3;
      if(VAR==2){
        uint2 v = *(const uint2*)&add[base+e];
        a0 += bf2f((ushort_t)(v.x&0xffff));
        a1 += bf2f((ushort_t)(v.x>>16));
        a2 += bf2f((ushort_t)(v.y&0xffff));
        a3 += bf2f((ushort_t)(v.y>>16));
      }
      u.x = (unsigned)f2bf(a0) | ((unsigned)f2bf(a1)<<16);
      u.y = (unsigned)f2bf(a2) | ((unsigned)f2bf(a3)<<16);
      *(uint2*)&outb[base+e] = u;
    }
  }
}

extern "C" void kernel_launch(void* const* d_in, const int* in_sizes, int n_in,
                              void* d_out, int out_size, void* d_ws, size_t ws_size,
                              hipStream_t stream){
  const float* x    = (const float*)d_in[0];
  const float* wqr  = (const float*)d_in[1];
  const float* wvr  = (const float*)d_in[2];
  const float* wup  = (const float*)d_in[3];
  const float* bup  = (const float*)d_in[4];
  const float* wql  = (const float*)d_in[5];
  const float* wvl  = (const float*)d_in[6];
  const float* crwq = (const float*)d_in[7];
  const float* crbq = (const float*)d_in[8];
  const float* crwk = (const float*)d_in[9];
  const float* crbk = (const float*)d_in[10];
  const float* crwv = (const float*)d_in[11];
  const float* crbv = (const float*)d_in[12];
  const float* gma  = (const float*)d_in[13];
  float* out = (float*)d_out;

  char* wsb = (char*)d_ws;
  ushort_t* TT   = (ushort_t*)wsb; wsb += 2*XSZk*2;   // T1 | T2 (T2 also final staging)
  ushort_t* VB2  = (ushort_t*)wsb; wsb += XSZk*2;
  ushort_t* VT2  = (ushort_t*)wsb; wsb += XSZk*2;
  ushort_t* Y2   = (ushort_t*)wsb; wsb += YSZk*2;
  ushort_t* Yt2  = (ushort_t*)wsb; wsb += YSZk*2;
  ushort_t* ATTL = (ushort_t*)wsb; wsb += ATTSZ*2;
  ushort_t* ATTR = (ushort_t*)wsb; wsb += ATTSZ*2;
  float*    partp= (float*)wsb;    wsb += (size_t)16*Bn*Nn*4;
  ushort_t* Wpb  = (ushort_t*)wsb; wsb += 320*Cn*2;
  float*    bp   = (float*)wsb;    wsb += 320*4;
  float*    xmean= (float*)wsb;    wsb += Bn*Cn*4;
  float*    wvec = (float*)wsb;    wsb += Bn*Cn*4;
  float*    xw   = (float*)wsb;    wsb += Bn*Cn*4;
  float*    g1   = (float*)wsb;    wsb += Bn*Cn*4;
  float*    mraw = (float*)wsb;    wsb += (size_t)PIXn*4;
  float*    maskb= (float*)wsb;    wsb += (size_t)PIXn*4;
  float*    craw = (float*)wsb;    wsb += (size_t)PIXn*4;
  float*    m2   = (float*)wsb;    wsb += (size_t)PIXn*4;
  ushort_t* XB   = (ushort_t*)wsb;  // +75.5MB only if useXB
  const int useXB = (ws_size >= (size_t)484000000) ? 1 : 0;

  k_packb<<<320,256,0,stream>>>(crwq,crbq,crwk,crbk,crwv,crbv,Wpb,bp);

  // ---- gating reductions (gates fused downstream) ----
  if(useXB) k_pass1<1><<<dim3(16,Bn),1024,0,stream>>>(x, wqr, xmean, partp, XB);
  else      k_pass1<0><<<dim3(16,Bn),1024,0,stream>>>(x, wqr, xmean, partp, nullptr);
  k_red16<<<Bn*Nn/256,256,0,stream>>>(partp, mraw);
  k_sn1<<<32,1024,0,stream>>>(mraw, maskb, xmean, wql, wvl, wvec);
  if(useXB) k_pass2<1><<<dim3(16,Bn),1024,0,stream>>>(nullptr, XB, wvec, maskb, xw, partp);
  else      k_pass2<0><<<dim3(16,Bn),1024,0,stream>>>(x, nullptr, wvec, maskb, xw, partp);
  k_red16<<<Bn*Nn/256,256,0,stream>>>(partp, craw);
  k_sn2<<<32,1024,0,stream>>>(craw, m2, xw, wvr, wup, bup, g1);

  ushort_t* T2p = TT + XSZk;

  // gated cross for one sel: TT[sel] = gm*VA_w + x*gate ; VT2 = OT (pvh^T)
  auto crossg = [&](int sel){
    if(useXB) k_gemm_qkv<1,1><<<dim3(Nn/64,Bn),256,0,stream>>>(nullptr, nullptr, XB, g1, m2, Wpb, bp, Y2, VB2, sel);
    else      k_gemm_qkv<1,0><<<dim3(Nn/64,Bn),256,0,stream>>>(nullptr, x, nullptr, g1, m2, Wpb, bp, Y2, VB2, sel);
    k_tr2<<<Bn*64 + Bn*Cn,256,0,stream>>>(Y2, Yt2, VB2, VT2);   // Y^T and V^T in one dispatch
    k_e2<<<dim3(96,2,Bn),256,0,stream>>>(Y2, Yt2, ATTL, ATTR);
    ushort_t* To = TT + (size_t)sel*XSZk;
    if(useXB) k_pv2<0,1><<<dim3(96,4,Bn),256,0,stream>>>(VB2, VT2, ATTL, ATTR, nullptr, XB, g1, m2, nullptr, To, VT2, gma, sel);
    else      k_pv2<0,0><<<dim3(96,4,Bn),256,0,stream>>>(VB2, VT2, ATTL, ATTR, x, nullptr, g1, m2, nullptr, To, VT2, gma, sel);
  };

  crossg(0);
  k_merge<0><<<Bn*Cn,256,0,stream>>>(nullptr, TT, nullptr, VT2);   // T1 += OT^T
  crossg(1);
  k_merge<2><<<Bn*Cn,256,0,stream>>>(nullptr, TT, T2p, VT2);       // T1 += T2 + OT^T

  // ---- final cross on T1 -> bf16 staging in T2 slot -> fp32 out ----
  k_gemm_qkv<0,0><<<dim3(Nn/64,Bn),256,0,stream>>>(TT, nullptr, nullptr, nullptr, nullptr, Wpb, bp, Y2, VB2, 0);
  k_tr2<<<Bn*64 + Bn*Cn,256,0,stream>>>(Y2, Yt2, VB2, VT2);
  k_e2<<<dim3(96,2,Bn),256,0,stream>>>(Y2, Yt2, ATTL, ATTR);
  k_pv2<1,0><<<dim3(96,4,Bn),256,0,stream>>>(VB2, VT2, ATTL, ATTR,
      nullptr, nullptr, nullptr, nullptr, /*residb=T1*/TT, /*To*/T2p, VT2, gma, 0);
  k_merge<4><<<Bn*Cn,256,0,stream>>>(out, nullptr, T2p, VT2);      // out = T2 + OT^T
}

// Round 15
// 1062.151 us; speedup vs baseline: 1.1267x; 1.1267x over previous
//
#include <hip/hip_runtime.h>
#include <math.h>

#define Bn 16
#define Cn 256
#define Hn 96
#define Wn 96
#define Nn 9216
#define PIXn 147456
#define XSZk ((size_t)Bn*Cn*Nn)
#define YSZk ((size_t)Bn*64*Nn)
#define ATTSZ ((size_t)PIXn*96)

typedef short bf8 __attribute__((ext_vector_type(8)));
typedef float f32x4 __attribute__((ext_vector_type(4)));
#define MFMA(a,b,c) __builtin_amdgcn_mfma_f32_16x16x32_bf16(a,b,c,0,0,0)

typedef unsigned short ushort_t;
typedef _Float16 h16;

__device__ inline ushort_t f2bf(float f){
  union{float f; unsigned int u;} v; v.f=f;
  unsigned int r = v.u + 0x7fffu + ((v.u>>16)&1u);
  return (ushort_t)(r>>16);
}
__device__ inline float bf2f(ushort_t s){
  union{unsigned int u; float f;} v; v.u = ((unsigned int)s)<<16;
  return v.f;
}
__device__ inline ushort_t f2h(float f){
  union{h16 h; ushort_t u;} v; v.h=(h16)f; return v.u;
}
__device__ inline float h2f(ushort_t u){
  union{ushort_t u; h16 h;} v; v.u=u; return (float)v.h;
}

__device__ inline float waveSum(float v){
#pragma unroll
  for(int o=32;o;o>>=1) v += __shfl_down(v,o,64);
  return v;
}
__device__ inline float waveMax(float v){
#pragma unroll
  for(int o=32;o;o>>=1) v = fmaxf(v,__shfl_down(v,o,64));
  return v;
}

// ---------------- gating ----------------

template<int XBW>
__global__ __launch_bounds__(1024) void k_pass1(const float* __restrict__ x,
    const float* __restrict__ wqr, float* __restrict__ xmean,
    float* __restrict__ partp, ushort_t* __restrict__ XB){
  int cg = blockIdx.x, b = blockIdx.y, tid = threadIdx.x;
  __shared__ float r16[16];
  float mp[2][8];
#pragma unroll
  for(int u=0;u<2;u++)
#pragma unroll
    for(int e=0;e<8;e++) mp[u][e]=0.f;
  for(int cc=0;cc<16;cc++){
    int c = cg*16+cc;
    const float* row = x + ((size_t)b*Cn + c)*Nn;
    float w = wqr[c];
    float s = 0.f;
#pragma unroll
    for(int u=0;u<2;u++){
      int ch = tid + u*1024;
      if(ch < 1152){
        float4 a = *(const float4*)&row[ch*8];
        float4 d = *(const float4*)&row[ch*8+4];
        float v0=a.x,v1=a.y,v2=a.z,v3=a.w,v4=d.x,v5=d.y,v6=d.z,v7=d.w;
        s += ((v0+v1)+(v2+v3))+((v4+v5)+(v6+v7));
        mp[u][0]+=w*v0; mp[u][1]+=w*v1; mp[u][2]+=w*v2; mp[u][3]+=w*v3;
        mp[u][4]+=w*v4; mp[u][5]+=w*v5; mp[u][6]+=w*v6; mp[u][7]+=w*v7;
        if(XBW){
          uint4 pk;
          pk.x=(unsigned)f2bf(v0)|((unsigned)f2bf(v1)<<16);
          pk.y=(unsigned)f2bf(v2)|((unsigned)f2bf(v3)<<16);
          pk.z=(unsigned)f2bf(v4)|((unsigned)f2bf(v5)<<16);
          pk.w=(unsigned)f2bf(v6)|((unsigned)f2bf(v7)<<16);
          *(uint4*)&XB[((size_t)b*Cn + c)*Nn + ch*8] = pk;
        }
      }
    }
    s = waveSum(s);
    if((tid&63)==0) r16[tid>>6]=s;
    __syncthreads();
    if(tid==0){
      float t=0.f;
      for(int i=0;i<16;i++) t+=r16[i];
      xmean[(size_t)b*Cn + c] = t*(1.f/Nn);
    }
    __syncthreads();
  }
  float* dst = partp + ((size_t)cg*Bn + b)*Nn;
#pragma unroll
  for(int u=0;u<2;u++){
    int ch = tid + u*1024;
    if(ch < 1152){
      float4 o1, o2;
      o1.x=mp[u][0]; o1.y=mp[u][1]; o1.z=mp[u][2]; o1.w=mp[u][3];
      o2.x=mp[u][4]; o2.y=mp[u][5]; o2.z=mp[u][6]; o2.w=mp[u][7];
      *(float4*)&dst[ch*8]   = o1;
      *(float4*)&dst[ch*8+4] = o2;
    }
  }
}

template<int XBR>
__global__ __launch_bounds__(1024) void k_pass2(const float* __restrict__ x,
    const ushort_t* __restrict__ XB, const float* __restrict__ wvec,
    const float* __restrict__ maskb, float* __restrict__ xw,
    float* __restrict__ partp){
  int cg = blockIdx.x, b = blockIdx.y, tid = threadIdx.x;
  __shared__ float r16[16];
  float cp[2][8], mk[2][8];
#pragma unroll
  for(int u=0;u<2;u++){
    int ch = tid + u*1024;
    if(ch < 1152){
      float4 a = *(const float4*)&maskb[(size_t)b*Nn + ch*8];
      float4 d = *(const float4*)&maskb[(size_t)b*Nn + ch*8 + 4];
      mk[u][0]=a.x; mk[u][1]=a.y; mk[u][2]=a.z; mk[u][3]=a.w;
      mk[u][4]=d.x; mk[u][5]=d.y; mk[u][6]=d.z; mk[u][7]=d.w;
    }
#pragma unroll
    for(int e=0;e<8;e++) cp[u][e]=0.f;
  }
  for(int cc=0;cc<16;cc++){
    int c = cg*16+cc;
    float w = wvec[(size_t)b*Cn + c];
    float s = 0.f;
#pragma unroll
    for(int u=0;u<2;u++){
      int ch = tid + u*1024;
      if(ch < 1152){
        float v[8];
        if(XBR){
          uint4 q = *(const uint4*)&XB[((size_t)b*Cn + c)*Nn + ch*8];
          unsigned* qp=(unsigned*)&q;
#pragma unroll
          for(int k=0;k<4;k++){
            v[2*k]   = bf2f((ushort_t)(qp[k]&0xffff));
            v[2*k+1] = bf2f((ushort_t)(qp[k]>>16));
          }
        } else {
          const float* row = x + ((size_t)b*Cn + c)*Nn;
          float4 a = *(const float4*)&row[ch*8];
          float4 d = *(const float4*)&row[ch*8+4];
          v[0]=a.x; v[1]=a.y; v[2]=a.z; v[3]=a.w;
          v[4]=d.x; v[5]=d.y; v[6]=d.z; v[7]=d.w;
        }
#pragma unroll
        for(int e=0;e<8;e++){
          s += mk[u][e]*v[e];
          cp[u][e] += w*v[e];
        }
      }
    }
    s = waveSum(s);
    if((tid&63)==0) r16[tid>>6]=s;
    __syncthreads();
    if(tid==0){
      float t=0.f;
      for(int i=0;i<16;i++) t+=r16[i];
      xw[(size_t)b*Cn + c] = t;
    }
    __syncthreads();
  }
  float* dst = partp + ((size_t)cg*Bn + b)*Nn;
#pragma unroll
  for(int u=0;u<2;u++){
    int ch = tid + u*1024;
    if(ch < 1152){
      float4 o1, o2;
      o1.x=cp[u][0]; o1.y=cp[u][1]; o1.z=cp[u][2]; o1.w=cp[u][3];
      o2.x=cp[u][4]; o2.y=cp[u][5]; o2.z=cp[u][6]; o2.w=cp[u][7];
      *(float4*)&dst[ch*8]   = o1;
      *(float4*)&dst[ch*8+4] = o2;
    }
  }
}

__global__ void k_red16(const float* __restrict__ part, float* __restrict__ out){
  size_t p = (size_t)blockIdx.x*256 + threadIdx.x;
  float s=0.f;
#pragma unroll
  for(int cg=0;cg<16;cg++) s += part[(size_t)cg*Bn*Nn + p];
  out[p]=s;
}

__device__ inline void softmax_n_body(const float* __restrict__ in,
    float* __restrict__ out, int b, int mode){
  int tid=threadIdx.x, lane=tid&63, wid=tid>>6;
  const float* p = in + (size_t)b*Nn;
  __shared__ float red[16];
  __shared__ float bc2[2];
  float mx=-3e38f;
  for(int i=tid;i<Nn;i+=1024) mx=fmaxf(mx,p[i]);
  mx = waveMax(mx);
  if(lane==0) red[wid]=mx;
  __syncthreads();
  if(tid==0){ float m=red[0]; for(int i=1;i<16;i++) m=fmaxf(m,red[i]); bc2[0]=m; }
  __syncthreads();
  mx=bc2[0];
  float s=0.f;
  for(int i=tid;i<Nn;i+=1024) s+=expf(p[i]-mx);
  s = waveSum(s);
  __syncthreads();
  if(lane==0) red[wid]=s;
  __syncthreads();
  if(tid==0){ float t=0.f; for(int i=0;i<16;i++) t+=red[i]; bc2[1]=t; }
  __syncthreads();
  float inv=1.f/bc2[1];
  for(int i=tid;i<Nn;i+=1024){
    float e=expf(p[i]-mx)*inv;
    out[(size_t)b*Nn+i] = mode ? 1.f/(1.f+expf(-e)) : e;
  }
}

__global__ __launch_bounds__(1024) void k_sn1(const float* __restrict__ mraw,
    float* __restrict__ maskb, const float* __restrict__ xmean,
    const float* __restrict__ wql, const float* __restrict__ wvl,
    float* __restrict__ wvec){
  if(blockIdx.x < 16){
    softmax_n_body(mraw, maskb, blockIdx.x, 0);
  } else {
    int b = blockIdx.x - 16, t = threadIdx.x;
    __shared__ float xm[Cn];
    __shared__ float av[128];
    if(t<Cn) xm[t] = xmean[b*Cn+t];
    __syncthreads();
    if(t<128){
      float s=0.f;
      for(int c=0;c<Cn;c++) s += wql[t*Cn+c]*xm[c];
      av[t]=s;
    }
    __syncthreads();
    if(t<Cn){
      float s=0.f;
      for(int m=0;m<128;m++) s += av[m]*wvl[m*Cn+t];
      wvec[b*Cn+t]=s;
    }
  }
}

__global__ __launch_bounds__(1024) void k_sn2(const float* __restrict__ craw,
    float* __restrict__ m2, const float* __restrict__ xw,
    const float* __restrict__ wvr, const float* __restrict__ wup,
    const float* __restrict__ bup, float* __restrict__ g1){
  if(blockIdx.x < 16){
    softmax_n_body(craw, m2, blockIdx.x, 1);
  } else {
    int b = blockIdx.x - 16, t = threadIdx.x;
    __shared__ float xs[Cn];
    __shared__ float cx[128];
    if(t<Cn) xs[t]=xw[b*Cn+t];
    __syncthreads();
    if(t<128){
      float s=0.f;
      for(int c=0;c<Cn;c++) s += wvr[t*Cn+c]*xs[c];
      cx[t]=s;
    }
    __syncthreads();
    if(t<Cn){
      float s=bup[t];
      for(int m=0;m<128;m++) s += wup[t*128+m]*cx[m];
      g1[b*Cn+t]=1.f/(1.f+expf(-s));
    }
  }
}

// ---------------- cross-attention, MFMA ----------------

__global__ void k_packb(const float* __restrict__ wq, const float* __restrict__ bq,
                        const float* __restrict__ wk, const float* __restrict__ bk,
                        const float* __restrict__ wv, const float* __restrict__ bv,
                        ushort_t* __restrict__ Wp, float* __restrict__ bp){
  int o = blockIdx.x, t = threadIdx.x;
  const float* src; float bs;
  if(o<32){ src = wq + o*Cn; bs = bq[o]; }
  else if(o<64){ src = wk + (o-32)*Cn; bs = bk[o-32]; }
  else { src = wv + (o-64)*Cn; bs = bv[o-64]; }
  Wp[o*Cn+t] = f2bf(src[t]);
  if(t==0) bp[o] = bs;
}

#define AP 40
#define BP 264
#define GP 68

template<int GATED, int XBR>
__global__ __launch_bounds__(256) void k_gemm_qkv(
    const ushort_t* __restrict__ tb, const float* __restrict__ x,
    const ushort_t* __restrict__ XBp,
    const float* __restrict__ g1, const float* __restrict__ m2,
    const ushort_t* __restrict__ Wp, const float* __restrict__ bp,
    ushort_t* __restrict__ Yqk, ushort_t* __restrict__ Vb, int sel){
  __shared__ ushort_t SM[320*AP + 64*BP];
  __shared__ float gsh[256];
  ushort_t* Ws = SM;
  ushort_t* Bt = SM + 320*AP;
  int b = blockIdx.y;
  int n0 = blockIdx.x*64;
  int tid = threadIdx.x, lane = tid&63, wid = tid>>6;

  if(GATED){
    gsh[tid] = g1[b*Cn + tid];
    __syncthreads();
    float scl_n = (sel==1) ? m2[(size_t)b*Nn + n0 + (tid&63)] : 0.f;
    int cg = (tid>>6)*8;
#pragma unroll
    for(int p=0;p<8;p++){
      int c8 = p*32 + cg;
      float fv[8];
      if(XBR){
        const ushort_t* xb = XBp + (size_t)b*Cn*Nn + n0 + (tid&63);
#pragma unroll
        for(int k2=0;k2<8;k2++){
          float xf = bf2f(xb[(size_t)(c8+k2)*Nn]);
          fv[k2] = xf * (sel==0 ? gsh[c8+k2] : scl_n);
        }
      } else {
        const float* xb = x + (size_t)b*Cn*Nn + n0 + (tid&63);
#pragma unroll
        for(int k2=0;k2<8;k2++){
          float xf = xb[(size_t)(c8+k2)*Nn];
          fv[k2] = xf * (sel==0 ? gsh[c8+k2] : scl_n);
        }
      }
      uint4 pk;
      pk.x = (unsigned)f2bf(fv[0]) | ((unsigned)f2bf(fv[1])<<16);
      pk.y = (unsigned)f2bf(fv[2]) | ((unsigned)f2bf(fv[3])<<16);
      pk.z = (unsigned)f2bf(fv[4]) | ((unsigned)f2bf(fv[5])<<16);
      pk.w = (unsigned)f2bf(fv[6]) | ((unsigned)f2bf(fv[7])<<16);
      *(uint4*)&Bt[(tid&63)*BP + c8] = pk;
    }
  } else {
    const ushort_t* xb = tb + (size_t)b*Cn*Nn + n0 + (tid&63);
    int cg = (tid>>6)*8;
#pragma unroll
    for(int p=0;p<8;p++){
      int c8 = p*32 + cg;
      unsigned e0=xb[(size_t)(c8+0)*Nn], e1=xb[(size_t)(c8+1)*Nn];
      unsigned e2=xb[(size_t)(c8+2)*Nn], e3=xb[(size_t)(c8+3)*Nn];
      unsigned e4=xb[(size_t)(c8+4)*Nn], e5=xb[(size_t)(c8+5)*Nn];
      unsigned e6=xb[(size_t)(c8+6)*Nn], e7=xb[(size_t)(c8+7)*Nn];
      uint4 pk;
      pk.x = e0 | (e1<<16); pk.y = e2 | (e3<<16);
      pk.z = e4 | (e5<<16); pk.w = e6 | (e7<<16);
      *(uint4*)&Bt[(tid&63)*BP + c8] = pk;
    }
  }

  f32x4 acc[5][4];
#pragma unroll
  for(int f=0;f<5;f++)
#pragma unroll
    for(int g=0;g<4;g++) acc[f][g] = (f32x4){0.f,0.f,0.f,0.f};

  for(int ki=0;ki<8;ki++){
    __syncthreads();
#pragma unroll
    for(int q=0;q<5;q++){
      int fidx = q*256 + tid;
      int o = fidx>>2, kk = (fidx&3)*8;
      uint4 wv = *(const uint4*)&Wp[o*Cn + ki*32 + kk];
      *(uint4*)&Ws[o*AP + kk] = wv;
    }
    __syncthreads();
    bf8 bfr[4];
#pragma unroll
    for(int g=0;g<4;g++)
      bfr[g] = *(const bf8*)&Bt[(g*16 + (lane&15))*BP + ki*32 + (lane>>4)*8];
#pragma unroll
    for(int f=0;f<5;f++){
      bf8 a = *(const bf8*)&Ws[(wid*80 + f*16 + (lane&15))*AP + (lane>>4)*8];
#pragma unroll
      for(int g=0;g<4;g++) acc[f][g] = MFMA(a, bfr[g], acc[f][g]);
    }
  }

  __syncthreads();
#pragma unroll
  for(int f=0;f<5;f++){
    int o = wid*80 + f*16 + (lane>>4)*4;
#pragma unroll
    for(int i=0;i<4;i++){
      float bias = bp[o+i];
#pragma unroll
      for(int g=0;g<4;g++)
        SM[(o+i)*GP + g*16 + (lane&15)] = f2bf(acc[f][g][i] + bias);
    }
  }
  __syncthreads();
  for(int u=tid; u<320*8; u+=256){
    int lo_ = u>>3, c8 = (u&7)*8;
    ushort_t* dst = (lo_<64) ? (Yqk + ((size_t)b*64 + lo_)*Nn)
                             : (Vb + ((size_t)b*Cn + (lo_-64))*Nn);
    *(uint4*)&dst[n0 + c8] = *(uint4*)&SM[lo_*GP + c8];
  }
}

// per-plane 96x96 bf16 transpose (standalone, used for Y)
__global__ __launch_bounds__(256) void k_transpose_b(const ushort_t* __restrict__ src,
                                                     ushort_t* __restrict__ dst){
  __shared__ ushort_t Ls[96*98];
  size_t base = (size_t)blockIdx.x * Nn;
  int tid = threadIdx.x;
  for(int e=tid*2; e<Nn; e+=512){
    unsigned int u = *(const unsigned int*)&src[base+e];
    int r=e/96, c=e%96;
    *(unsigned int*)&Ls[r*98+c] = u;
  }
  __syncthreads();
  for(int e=tid*2; e<Nn; e+=512){
    int r=e/96, c=e%96;
    unsigned int u = (unsigned int)Ls[c*98+r] | (((unsigned int)Ls[(c+1)*98+r])<<16);
    *(unsigned int*)&dst[base+e] = u;
  }
}

// unified QK^T -> fp16 logits
__global__ __launch_bounds__(256) void k_e2(const ushort_t* __restrict__ Yqk,
    const ushort_t* __restrict__ Yqkt, ushort_t* __restrict__ attl,
    ushort_t* __restrict__ attr){
  __shared__ ushort_t Qt[96*AP];
  __shared__ ushort_t Kt[96*AP];
  int r = blockIdx.x, mode = blockIdx.y, b = blockIdx.z;
  const ushort_t* Y = mode ? Yqk : Yqkt;
  int pm   = mode ? 1  : 96;
  int pr   = mode ? 96 : 1;
  ushort_t* attx = mode ? attr : attl;
  int tid = threadIdx.x, lane = tid&63, wid = tid>>6;
  {
    int half = tid>>7;
    int cg   = (tid>>5)&3;
    int l32  = tid&31;
    ushort_t* T = half ? Kt : Qt;
    const ushort_t* S = Y + ((size_t)b*64 + half*32 + cg*8)*Nn + (size_t)r*96;
#pragma unroll
    for(int p=0;p<3;p++){
      int sp = p*32 + l32;
      unsigned e0=S[(size_t)0*Nn+sp], e1=S[(size_t)1*Nn+sp];
      unsigned e2=S[(size_t)2*Nn+sp], e3=S[(size_t)3*Nn+sp];
      unsigned e4=S[(size_t)4*Nn+sp], e5=S[(size_t)5*Nn+sp];
      unsigned e6=S[(size_t)6*Nn+sp], e7=S[(size_t)7*Nn+sp];
      uint4 pk;
      pk.x = e0 | (e1<<16); pk.y = e2 | (e3<<16);
      pk.z = e4 | (e5<<16); pk.w = e6 | (e7<<16);
      *(uint4*)&T[sp*AP + cg*8] = pk;
    }
  }
  __syncthreads();
  int mb = (wid>>1)*48, nb = (wid&1)*48;
  const f32x4 z4 = {0.f,0.f,0.f,0.f};
  f32x4 acc[3][3];
  bf8 a[3], bb[3];
#pragma unroll
  for(int f=0;f<3;f++) a[f] = *(const bf8*)&Qt[(mb+f*16+(lane&15))*AP + (lane>>4)*8];
#pragma unroll
  for(int g=0;g<3;g++) bb[g] = *(const bf8*)&Kt[(nb+g*16+(lane&15))*AP + (lane>>4)*8];
#pragma unroll
  for(int f=0;f<3;f++)
#pragma unroll
    for(int g=0;g<3;g++) acc[f][g] = MFMA(a[f], bb[g], z4);
#pragma unroll
  for(int f=0;f<3;f++)
#pragma unroll
    for(int i=0;i<4;i++){
      int m = mb + f*16 + (lane>>4)*4 + i;
      ushort_t* arow = attx + ((size_t)b*Nn + (size_t)m*pm + (size_t)r*pr)*96;
#pragma unroll
      for(int g=0;g<3;g++){
        int n = nb + g*16 + (lane&15);
        arow[n] = f2h(acc[f][g][i]);
      }
    }
}

// fused: softmax_ip (blocks x<1164) || per-plane V transpose (x>=1164)
__global__ __launch_bounds__(256) void k_smvt(ushort_t* attl, ushort_t* attr,
    const ushort_t* __restrict__ Vsrc, ushort_t* __restrict__ Vdst){
  __shared__ ushort_t Ls[96*98];
  int b = blockIdx.z;
  if(blockIdx.x < 1164){
    int wave = threadIdx.x>>6, l = threadIdx.x&63;
    int t = blockIdx.x*4 + wave;               // 0..4655
    int i=0, base=0;
    while(base + (96-i) <= t){ base += 96-i; i++; }
    int j = i + (t-base);
    int hf = l>>5, l32 = l&31;
    int h = hf ? j : i, w = hf ? i : j;
    size_t p = (size_t)b*Nn + (size_t)h*96 + w;
    const ushort_t* al = attl + p*96;
    const ushort_t* ar = attr + p*96;
    float v[6];
#pragma unroll
    for(int k=0;k<3;k++){
      int el = l32 + 32*k;
      float vv = h2f(al[el]);
      v[k] = (el==h) ? -1e30f : vv;
    }
#pragma unroll
    for(int k=0;k<3;k++) v[3+k] = h2f(ar[l32 + 32*k]);
    float mx = v[0];
#pragma unroll
    for(int k=1;k<6;k++) mx = fmaxf(mx, v[k]);
#pragma unroll
    for(int o=16;o;o>>=1) mx = fmaxf(mx, __shfl_xor(mx, o, 64));
    float e[6], s=0.f;
#pragma unroll
    for(int k=0;k<6;k++){ e[k]=expf(v[k]-mx); s+=e[k]; }
#pragma unroll
    for(int o=16;o;o>>=1) s += __shfl_xor(s, o, 64);
    float inv = 1.f/s;
    size_t q = (size_t)b*Nn + (size_t)w*96 + h;
    ushort_t* oh = attl + q*96;
    ushort_t* ow = attr + p*96;
#pragma unroll
    for(int k=0;k<3;k++) oh[l32+32*k] = f2bf(e[k]*inv);
#pragma unroll
    for(int k=0;k<3;k++) ow[l32+32*k] = f2bf(e[3+k]*inv);
  } else {
    int c = blockIdx.x - 1164;
    size_t base = ((size_t)b*Cn + c) * Nn;
    int tid = threadIdx.x;
    for(int e=tid*2; e<Nn; e+=512){
      unsigned int u = *(const unsigned int*)&Vsrc[base+e];
      int r=e/96, cc=e%96;
      *(unsigned int*)&Ls[r*98+cc] = u;
    }
    __syncthreads();
    for(int e=tid*2; e<Nn; e+=512){
      int r=e/96, cc=e%96;
      unsigned int u = (unsigned int)Ls[cc*98+r] | (((unsigned int)Ls[(cc+1)*98+r])<<16);
      *(unsigned int*)&Vdst[base+e] = u;
    }
  }
}

#define SP 104   // att staging pitch (2-way only, free)
#define RP 100   // repack pitch (64-row buffer)

// unified PV, 256 thr, 128 ch/block: blockIdx.y = mode*2+half
template<int RES, int XBR>
__global__ __launch_bounds__(256) void k_pv2(const ushort_t* __restrict__ VB,
    const ushort_t* __restrict__ VTb, const ushort_t* __restrict__ attw,
    const ushort_t* __restrict__ atth, const float* __restrict__ x,
    const ushort_t* __restrict__ XBp,
    const float* __restrict__ g1, const float* __restrict__ m2,
    const ushort_t* __restrict__ residb, ushort_t* __restrict__ Tob,
    ushort_t* __restrict__ OTb, const float* __restrict__ gp, int sel){
  __shared__ ushort_t SMEM[96*SP];    // 19968B; repack 64*RP=12800B fits
  int r = blockIdx.x, mode = blockIdx.y>>1, half = blockIdx.y&1, b = blockIdx.z;
  float gm = gp[0];
  int tid = threadIdx.x, lane = tid&63, wid = tid>>6;
  const ushort_t* V = mode ? VTb : VB;
  size_t vbase = (size_t)b*Cn*Nn + (size_t)r*96;
  // prefetch V fragments (before staging; hides HBM latency)
  bf8 vf[6];
#pragma unroll
  for(int f=0;f<2;f++)
#pragma unroll
    for(int j=0;j<3;j++)
      vf[f*3+j] = *(const bf8*)&V[vbase
        + (size_t)(half*128 + wid*32 + f*16 + (lane&15))*Nn + j*32 + (lane>>4)*8];
  const ushort_t* ab = (mode ? atth : attw) + ((size_t)b*Nn + (size_t)r*96)*96;
  for(int u=tid; u<96*12; u+=256){
    int n=u/12, j8=(u%12)*8;
    uint4 q = *(const uint4*)&ab[n*96 + j8];
    *(uint4*)&SMEM[n*SP + j8] = q;
  }
  __syncthreads();
  f32x4 acc[2][6];
#pragma unroll
  for(int f=0;f<2;f++)
#pragma unroll
    for(int g=0;g<6;g++) acc[f][g] = (f32x4){0.f,0.f,0.f,0.f};
#pragma unroll
  for(int j0=0;j0<3;j0++){
    bf8 bfr[6];
#pragma unroll
    for(int g=0;g<6;g++)
      bfr[g] = *(const bf8*)&SMEM[(g*16+(lane&15))*SP + j0*32 + (lane>>4)*8];
#pragma unroll
    for(int f=0;f<2;f++)
#pragma unroll
      for(int g=0;g<6;g++) acc[f][g] = MFMA(vf[f*3+j0], bfr[g], acc[f][g]);
  }
  // epilogue: two f-phases, all 4 waves active; 64-row repack buffer
#pragma unroll
  for(int ph=0; ph<2; ph++){
    __syncthreads();
    {
      int f = ph;
      int rl = wid*16 + (lane>>4)*4;           // local row base 0..63
#pragma unroll
      for(int i=0;i<4;i++)
#pragma unroll
        for(int g=0;g<6;g++)
          SMEM[(rl+i)*RP + g*16 + (lane&15)] = f2bf(gm*acc[f][g][i]);
    }
    __syncthreads();
    for(int u=tid; u<64*12; u+=256){
      int rl = u/12, q8 = (u%12)*8;
      int c = half*128 + (rl>>4)*32 + ph*16 + (rl&15);
      size_t row = vbase + (size_t)c*Nn;
      uint4 v = *(uint4*)&SMEM[rl*RP + q8];
      if(mode){
        *(uint4*)&OTb[row + q8] = v;
      } else {
        unsigned* vp=(unsigned*)&v;
        float rs[8];
        if(RES==1){
          uint4 rv = *(const uint4*)&residb[row + q8];
          unsigned* rp=(unsigned*)&rv;
#pragma unroll
          for(int k=0;k<4;k++){
            rs[2*k]   = bf2f((ushort_t)(rp[k]&0xffff));
            rs[2*k+1] = bf2f((ushort_t)(rp[k]>>16));
          }
        } else {
          float xv[8];
          if(XBR){
            uint4 xq = *(const uint4*)&XBp[row + q8];
            unsigned* xp=(unsigned*)&xq;
#pragma unroll
            for(int k=0;k<4;k++){
              xv[2*k]   = bf2f((ushort_t)(xp[k]&0xffff));
              xv[2*k+1] = bf2f((ushort_t)(xp[k]>>16));
            }
          } else {
            float4 x1 = *(const float4*)&x[row + q8];
            float4 x2 = *(const float4*)&x[row + q8 + 4];
            xv[0]=x1.x; xv[1]=x1.y; xv[2]=x1.z; xv[3]=x1.w;
            xv[4]=x2.x; xv[5]=x2.y; xv[6]=x2.z; xv[7]=x2.w;
          }
          if(sel==0){
            float g = g1[b*Cn + c];
#pragma unroll
            for(int k=0;k<8;k++) rs[k] = xv[k]*g;
          } else {
            float4 m1 = *(const float4*)&m2[(size_t)b*Nn + (size_t)r*96 + q8];
            float4 m2v= *(const float4*)&m2[(size_t)b*Nn + (size_t)r*96 + q8 + 4];
            float mv[8] = {m1.x,m1.y,m1.z,m1.w,m2v.x,m2v.y,m2v.z,m2v.w};
#pragma unroll
            for(int k=0;k<8;k++) rs[k] = xv[k]*mv[k];
          }
        }
        uint4 o; unsigned* op=(unsigned*)&o;
#pragma unroll
        for(int k=0;k<4;k++){
          float lo = bf2f((ushort_t)(vp[k]&0xffff)) + rs[2*k];
          float hi = bf2f((ushort_t)(vp[k]>>16))    + rs[2*k+1];
          op[k] = (unsigned)f2bf(lo) | ((unsigned)f2bf(hi)<<16);
        }
        *(uint4*)&Tob[row + q8] = o;
      }
    }
  }
}

// merge: VAR 0: outb += OT^T ; VAR 2: outb += add + OT^T ; VAR 4: outf = add + OT^T
template<int VAR>
__global__ __launch_bounds__(256) void k_merge(float* __restrict__ outf,
    ushort_t* __restrict__ outb, const ushort_t* __restrict__ add,
    const ushort_t* __restrict__ OT){
  __shared__ ushort_t Ls[96*98];
  size_t base = (size_t)blockIdx.x * Nn;
  int tid = threadIdx.x;
  for(int e=tid*2; e<Nn; e+=512){
    int r=e/96, c=e%96;
    *(unsigned int*)&Ls[r*98+c] = *(const unsigned int*)&OT[base+e];
  }
  __syncthreads();
  for(int e=tid*4; e<Nn; e+=1024){
    int r=e/96, c=e%96;
    float t0 = bf2f(Ls[(c+0)*98+r]), t1 = bf2f(Ls[(c+1)*98+r]);
    float t2 = bf2f(Ls[(c+2)*98+r]), t3 = bf2f(Ls[(c+3)*98+r]);
    if(VAR==4){
      uint2 v = *(const uint2*)&add[base+e];
      float4 o;
      o.x = bf2f((ushort_t)(v.x&0xffff)) + t0;
      o.y = bf2f((ushort_t)(v.x>>16))    + t1;
      o.z = bf2f((ushort_t)(v.y&0xffff)) + t2;
      o.w = bf2f((ushort_t)(v.y>>16))    + t3;
      *(float4*)&outf[base+e] = o;
    } else {
      uint2 u = *(uint2*)&outb[base+e];
      float a0 = bf2f((ushort_t)(u.x&0xffff)) + t0;
      float a1 = bf2f((ushort_t)(u.x>>16))    + t1;
      float a2 = bf2f((ushort_t)(u.y&0xffff)) + t2;
      float a3 = bf2f((ushort_t)(u.y>>16))    + t3;
      if(VAR==2){
        uint2 v = *(const uint2*)&add[base+e];
        a0 += bf2f((ushort_t)(v.x&0xffff));
        a1 += bf2f((ushort_t)(v.x>>16));
        a2 += bf2f((ushort_t)(v.y&0xffff));
        a3 += bf2f((ushort_t)(v.y>>16));
      }
      u.x = (unsigned)f2bf(a0) | ((unsigned)f2bf(a1)<<16);
      u.y = (unsigned)f2bf(a2) | ((unsigned)f2bf(a3)<<16);
      *(uint2*)&outb[base+e] = u;
    }
  }
}

extern "C" void kernel_launch(void* const* d_in, const int* in_sizes, int n_in,
                              void* d_out, int out_size, void* d_ws, size_t ws_size,
                              hipStream_t stream){
  const float* x    = (const float*)d_in[0];
  const float* wqr  = (const float*)d_in[1];
  const float* wvr  = (const float*)d_in[2];
  const float* wup  = (const float*)d_in[3];
  const float* bup  = (const float*)d_in[4];
  const float* wql  = (const float*)d_in[5];
  const float* wvl  = (const float*)d_in[6];
  const float* crwq = (const float*)d_in[7];
  const float* crbq = (const float*)d_in[8];
  const float* crwk = (const float*)d_in[9];
  const float* crbk = (const float*)d_in[10];
  const float* crwv = (const float*)d_in[11];
  const float* crbv = (const float*)d_in[12];
  const float* gma  = (const float*)d_in[13];
  float* out = (float*)d_out;

  char* wsb = (char*)d_ws;
  ushort_t* TT   = (ushort_t*)wsb; wsb += 2*XSZk*2;   // T1 | T2 (T2 also final staging)
  ushort_t* VB2  = (ushort_t*)wsb; wsb += XSZk*2;
  ushort_t* VT2  = (ushort_t*)wsb; wsb += XSZk*2;
  ushort_t* Y2   = (ushort_t*)wsb; wsb += YSZk*2;
  ushort_t* Yt2  = (ushort_t*)wsb; wsb += YSZk*2;
  ushort_t* ATTL = (ushort_t*)wsb; wsb += ATTSZ*2;
  ushort_t* ATTR = (ushort_t*)wsb; wsb += ATTSZ*2;
  float*    partp= (float*)wsb;    wsb += (size_t)16*Bn*Nn*4;
  ushort_t* Wpb  = (ushort_t*)wsb; wsb += 320*Cn*2;
  float*    bp   = (float*)wsb;    wsb += 320*4;
  float*    xmean= (float*)wsb;    wsb += Bn*Cn*4;
  float*    wvec = (float*)wsb;    wsb += Bn*Cn*4;
  float*    xw   = (float*)wsb;    wsb += Bn*Cn*4;
  float*    g1   = (float*)wsb;    wsb += Bn*Cn*4;
  float*    mraw = (float*)wsb;    wsb += (size_t)PIXn*4;
  float*    maskb= (float*)wsb;    wsb += (size_t)PIXn*4;
  float*    craw = (float*)wsb;    wsb += (size_t)PIXn*4;
  float*    m2   = (float*)wsb;    wsb += (size_t)PIXn*4;
  ushort_t* XB   = (ushort_t*)wsb;  // +75.5MB only if useXB
  const int useXB = (ws_size >= (size_t)484000000) ? 1 : 0;

  k_packb<<<320,256,0,stream>>>(crwq,crbq,crwk,crbk,crwv,crbv,Wpb,bp);

  // ---- gating reductions (gates fused downstream) ----
  if(useXB) k_pass1<1><<<dim3(16,Bn),1024,0,stream>>>(x, wqr, xmean, partp, XB);
  else      k_pass1<0><<<dim3(16,Bn),1024,0,stream>>>(x, wqr, xmean, partp, nullptr);
  k_red16<<<Bn*Nn/256,256,0,stream>>>(partp, mraw);
  k_sn1<<<32,1024,0,stream>>>(mraw, maskb, xmean, wql, wvl, wvec);
  if(useXB) k_pass2<1><<<dim3(16,Bn),1024,0,stream>>>(nullptr, XB, wvec, maskb, xw, partp);
  else      k_pass2<0><<<dim3(16,Bn),1024,0,stream>>>(x, nullptr, wvec, maskb, xw, partp);
  k_red16<<<Bn*Nn/256,256,0,stream>>>(partp, craw);
  k_sn2<<<32,1024,0,stream>>>(craw, m2, xw, wvr, wup, bup, g1);

  ushort_t* T2p = TT + XSZk;

  // gated cross for one sel: TT[sel] = gm*VA_w + x*gate ; VT2 = OT (pvh^T)
  auto crossg = [&](int sel){
    if(useXB) k_gemm_qkv<1,1><<<dim3(Nn/64,Bn),256,0,stream>>>(nullptr, nullptr, XB, g1, m2, Wpb, bp, Y2, VB2, sel);
    else      k_gemm_qkv<1,0><<<dim3(Nn/64,Bn),256,0,stream>>>(nullptr, x, nullptr, g1, m2, Wpb, bp, Y2, VB2, sel);
    k_transpose_b<<<Bn*64,256,0,stream>>>(Y2, Yt2);
    k_e2<<<dim3(96,2,Bn),256,0,stream>>>(Y2, Yt2, ATTL, ATTR);
    k_smvt<<<dim3(1164+256,1,Bn),256,0,stream>>>(ATTL, ATTR, VB2, VT2);  // softmax || V-transpose
    ushort_t* To = TT + (size_t)sel*XSZk;
    if(useXB) k_pv2<0,1><<<dim3(96,4,Bn),256,0,stream>>>(VB2, VT2, ATTR, ATTL, nullptr, XB, g1, m2, nullptr, To, VT2, gma, sel);
    else      k_pv2<0,0><<<dim3(96,4,Bn),256,0,stream>>>(VB2, VT2, ATTR, ATTL, x, nullptr, g1, m2, nullptr, To, VT2, gma, sel);
  };

  crossg(0);
  k_merge<0><<<Bn*Cn,256,0,stream>>>(nullptr, TT, nullptr, VT2);   // T1 += OT^T
  crossg(1);
  k_merge<2><<<Bn*Cn,256,0,stream>>>(nullptr, TT, T2p, VT2);       // T1 += T2 + OT^T

  // ---- final cross on T1 -> bf16 staging in T2 slot -> fp32 out ----
  k_gemm_qkv<0,0><<<dim3(Nn/64,Bn),256,0,stream>>>(TT, nullptr, nullptr, nullptr, nullptr, Wpb, bp, Y2, VB2, 0);
  k_transpose_b<<<Bn*64,256,0,stream>>>(Y2, Yt2);
  k_e2<<<dim3(96,2,Bn),256,0,stream>>>(Y2, Yt2, ATTL, ATTR);
  k_smvt<<<dim3(1164+256,1,Bn),256,0,stream>>>(ATTL, ATTR, VB2, VT2);
  k_pv2<1,0><<<dim3(96,4,Bn),256,0,stream>>>(VB2, VT2, ATTR, ATTL,
      nullptr, nullptr, nullptr, nullptr, /*residb=T1*/TT, /*To*/T2p, VT2, gma, 0);
  k_merge<4><<<Bn*Cn,256,0,stream>>>(out, nullptr, T2p, VT2);      // out = T2 + OT^T
}

// Round 16
// 1049.261 us; speedup vs baseline: 1.1405x; 1.0123x over previous
//
#include <hip/hip_runtime.h>
#include <math.h>

#define Bn 16
#define Cn 256
#define Hn 96
#define Wn 96
#define Nn 9216
#define PIXn 147456
#define XSZk ((size_t)Bn*Cn*Nn)
#define YSZk ((size_t)Bn*64*Nn)
#define ATTSZ ((size_t)PIXn*96)

typedef short bf8 __attribute__((ext_vector_type(8)));
typedef float f32x4 __attribute__((ext_vector_type(4)));
#define MFMA(a,b,c) __builtin_amdgcn_mfma_f32_16x16x32_bf16(a,b,c,0,0,0)

typedef unsigned short ushort_t;
typedef _Float16 h16;

__device__ inline ushort_t f2bf(float f){
  union{float f; unsigned int u;} v; v.f=f;
  unsigned int r = v.u + 0x7fffu + ((v.u>>16)&1u);
  return (ushort_t)(r>>16);
}
__device__ inline float bf2f(ushort_t s){
  union{unsigned int u; float f;} v; v.u = ((unsigned int)s)<<16;
  return v.f;
}
__device__ inline ushort_t f2h(float f){
  union{h16 h; ushort_t u;} v; v.h=(h16)f; return v.u;
}
__device__ inline float h2f(ushort_t u){
  union{ushort_t u; h16 h;} v; v.u=u; return (float)v.h;
}

__device__ inline float waveSum(float v){
#pragma unroll
  for(int o=32;o;o>>=1) v += __shfl_down(v,o,64);
  return v;
}
__device__ inline float waveMax(float v){
#pragma unroll
  for(int o=32;o;o>>=1) v = fmaxf(v,__shfl_down(v,o,64));
  return v;
}

// ---------------- gating ----------------

template<int XBW>
__global__ __launch_bounds__(1024) void k_pass1(const float* __restrict__ x,
    const float* __restrict__ wqr, float* __restrict__ xmean,
    float* __restrict__ partp, ushort_t* __restrict__ XB){
  int cg = blockIdx.x, b = blockIdx.y, tid = threadIdx.x;
  __shared__ float r16[16];
  float mp[2][8];
#pragma unroll
  for(int u=0;u<2;u++)
#pragma unroll
    for(int e=0;e<8;e++) mp[u][e]=0.f;
  for(int cc=0;cc<16;cc++){
    int c = cg*16+cc;
    const float* row = x + ((size_t)b*Cn + c)*Nn;
    float w = wqr[c];
    float s = 0.f;
#pragma unroll
    for(int u=0;u<2;u++){
      int ch = tid + u*1024;
      if(ch < 1152){
        float4 a = *(const float4*)&row[ch*8];
        float4 d = *(const float4*)&row[ch*8+4];
        float v0=a.x,v1=a.y,v2=a.z,v3=a.w,v4=d.x,v5=d.y,v6=d.z,v7=d.w;
        s += ((v0+v1)+(v2+v3))+((v4+v5)+(v6+v7));
        mp[u][0]+=w*v0; mp[u][1]+=w*v1; mp[u][2]+=w*v2; mp[u][3]+=w*v3;
        mp[u][4]+=w*v4; mp[u][5]+=w*v5; mp[u][6]+=w*v6; mp[u][7]+=w*v7;
        if(XBW){
          uint4 pk;
          pk.x=(unsigned)f2bf(v0)|((unsigned)f2bf(v1)<<16);
          pk.y=(unsigned)f2bf(v2)|((unsigned)f2bf(v3)<<16);
          pk.z=(unsigned)f2bf(v4)|((unsigned)f2bf(v5)<<16);
          pk.w=(unsigned)f2bf(v6)|((unsigned)f2bf(v7)<<16);
          *(uint4*)&XB[((size_t)b*Cn + c)*Nn + ch*8] = pk;
        }
      }
    }
    s = waveSum(s);
    if((tid&63)==0) r16[tid>>6]=s;
    __syncthreads();
    if(tid==0){
      float t=0.f;
      for(int i=0;i<16;i++) t+=r16[i];
      xmean[(size_t)b*Cn + c] = t*(1.f/Nn);
    }
    __syncthreads();
  }
  float* dst = partp + ((size_t)cg*Bn + b)*Nn;
#pragma unroll
  for(int u=0;u<2;u++){
    int ch = tid + u*1024;
    if(ch < 1152){
      float4 o1, o2;
      o1.x=mp[u][0]; o1.y=mp[u][1]; o1.z=mp[u][2]; o1.w=mp[u][3];
      o2.x=mp[u][4]; o2.y=mp[u][5]; o2.z=mp[u][6]; o2.w=mp[u][7];
      *(float4*)&dst[ch*8]   = o1;
      *(float4*)&dst[ch*8+4] = o2;
    }
  }
}

template<int XBR>
__global__ __launch_bounds__(1024) void k_pass2(const float* __restrict__ x,
    const ushort_t* __restrict__ XB, const float* __restrict__ wvec,
    const float* __restrict__ maskb, float* __restrict__ xw,
    float* __restrict__ partp){
  int cg = blockIdx.x, b = blockIdx.y, tid = threadIdx.x;
  __shared__ float r16[16];
  float cp[2][8], mk[2][8];
#pragma unroll
  for(int u=0;u<2;u++){
    int ch = tid + u*1024;
    if(ch < 1152){
      float4 a = *(const float4*)&maskb[(size_t)b*Nn + ch*8];
      float4 d = *(const float4*)&maskb[(size_t)b*Nn + ch*8 + 4];
      mk[u][0]=a.x; mk[u][1]=a.y; mk[u][2]=a.z; mk[u][3]=a.w;
      mk[u][4]=d.x; mk[u][5]=d.y; mk[u][6]=d.z; mk[u][7]=d.w;
    }
#pragma unroll
    for(int e=0;e<8;e++) cp[u][e]=0.f;
  }
  for(int cc=0;cc<16;cc++){
    int c = cg*16+cc;
    float w = wvec[(size_t)b*Cn + c];
    float s = 0.f;
#pragma unroll
    for(int u=0;u<2;u++){
      int ch = tid + u*1024;
      if(ch < 1152){
        float v[8];
        if(XBR){
          uint4 q = *(const uint4*)&XB[((size_t)b*Cn + c)*Nn + ch*8];
          unsigned* qp=(unsigned*)&q;
#pragma unroll
          for(int k=0;k<4;k++){
            v[2*k]   = bf2f((ushort_t)(qp[k]&0xffff));
            v[2*k+1] = bf2f((ushort_t)(qp[k]>>16));
          }
        } else {
          const float* row = x + ((size_t)b*Cn + c)*Nn;
          float4 a = *(const float4*)&row[ch*8];
          float4 d = *(const float4*)&row[ch*8+4];
          v[0]=a.x; v[1]=a.y; v[2]=a.z; v[3]=a.w;
          v[4]=d.x; v[5]=d.y; v[6]=d.z; v[7]=d.w;
        }
#pragma unroll
        for(int e=0;e<8;e++){
          s += mk[u][e]*v[e];
          cp[u][e] += w*v[e];
        }
      }
    }
    s = waveSum(s);
    if((tid&63)==0) r16[tid>>6]=s;
    __syncthreads();
    if(tid==0){
      float t=0.f;
      for(int i=0;i<16;i++) t+=r16[i];
      xw[(size_t)b*Cn + c] = t;
    }
    __syncthreads();
  }
  float* dst = partp + ((size_t)cg*Bn + b)*Nn;
#pragma unroll
  for(int u=0;u<2;u++){
    int ch = tid + u*1024;
    if(ch < 1152){
      float4 o1, o2;
      o1.x=cp[u][0]; o1.y=cp[u][1]; o1.z=cp[u][2]; o1.w=cp[u][3];
      o2.x=cp[u][4]; o2.y=cp[u][5]; o2.z=cp[u][6]; o2.w=cp[u][7];
      *(float4*)&dst[ch*8]   = o1;
      *(float4*)&dst[ch*8+4] = o2;
    }
  }
}

__global__ void k_red16(const float* __restrict__ part, float* __restrict__ out){
  size_t p = (size_t)blockIdx.x*256 + threadIdx.x;
  float s=0.f;
#pragma unroll
  for(int cg=0;cg<16;cg++) s += part[(size_t)cg*Bn*Nn + p];
  out[p]=s;
}

__device__ inline void softmax_n_body(const float* __restrict__ in,
    float* __restrict__ out, int b, int mode){
  int tid=threadIdx.x, lane=tid&63, wid=tid>>6;
  const float* p = in + (size_t)b*Nn;
  __shared__ float red[16];
  __shared__ float bc2[2];
  float mx=-3e38f;
  for(int i=tid;i<Nn;i+=1024) mx=fmaxf(mx,p[i]);
  mx = waveMax(mx);
  if(lane==0) red[wid]=mx;
  __syncthreads();
  if(tid==0){ float m=red[0]; for(int i=1;i<16;i++) m=fmaxf(m,red[i]); bc2[0]=m; }
  __syncthreads();
  mx=bc2[0];
  float s=0.f;
  for(int i=tid;i<Nn;i+=1024) s+=expf(p[i]-mx);
  s = waveSum(s);
  __syncthreads();
  if(lane==0) red[wid]=s;
  __syncthreads();
  if(tid==0){ float t=0.f; for(int i=0;i<16;i++) t+=red[i]; bc2[1]=t; }
  __syncthreads();
  float inv=1.f/bc2[1];
  for(int i=tid;i<Nn;i+=1024){
    float e=expf(p[i]-mx)*inv;
    out[(size_t)b*Nn+i] = mode ? 1.f/(1.f+expf(-e)) : e;
  }
}

__global__ __launch_bounds__(1024) void k_sn1(const float* __restrict__ mraw,
    float* __restrict__ maskb, const float* __restrict__ xmean,
    const float* __restrict__ wql, const float* __restrict__ wvl,
    float* __restrict__ wvec){
  if(blockIdx.x < 16){
    softmax_n_body(mraw, maskb, blockIdx.x, 0);
  } else {
    int b = blockIdx.x - 16, t = threadIdx.x;
    __shared__ float xm[Cn];
    __shared__ float av[128];
    if(t<Cn) xm[t] = xmean[b*Cn+t];
    __syncthreads();
    if(t<128){
      float s=0.f;
      for(int c=0;c<Cn;c++) s += wql[t*Cn+c]*xm[c];
      av[t]=s;
    }
    __syncthreads();
    if(t<Cn){
      float s=0.f;
      for(int m=0;m<128;m++) s += av[m]*wvl[m*Cn+t];
      wvec[b*Cn+t]=s;
    }
  }
}

__global__ __launch_bounds__(1024) void k_sn2(const float* __restrict__ craw,
    float* __restrict__ m2, const float* __restrict__ xw,
    const float* __restrict__ wvr, const float* __restrict__ wup,
    const float* __restrict__ bup, float* __restrict__ g1){
  if(blockIdx.x < 16){
    softmax_n_body(craw, m2, blockIdx.x, 1);
  } else {
    int b = blockIdx.x - 16, t = threadIdx.x;
    __shared__ float xs[Cn];
    __shared__ float cx[128];
    if(t<Cn) xs[t]=xw[b*Cn+t];
    __syncthreads();
    if(t<128){
      float s=0.f;
      for(int c=0;c<Cn;c++) s += wvr[t*Cn+c]*xs[c];
      cx[t]=s;
    }
    __syncthreads();
    if(t<Cn){
      float s=bup[t];
      for(int m=0;m<128;m++) s += wup[t*128+m]*cx[m];
      g1[b*Cn+t]=1.f/(1.f+expf(-s));
    }
  }
}

// ---------------- cross-attention, MFMA ----------------

__global__ void k_packb(const float* __restrict__ wq, const float* __restrict__ bq,
                        const float* __restrict__ wk, const float* __restrict__ bk,
                        const float* __restrict__ wv, const float* __restrict__ bv,
                        ushort_t* __restrict__ Wp, float* __restrict__ bp){
  int o = blockIdx.x, t = threadIdx.x;
  const float* src; float bs;
  if(o<32){ src = wq + o*Cn; bs = bq[o]; }
  else if(o<64){ src = wk + (o-32)*Cn; bs = bk[o-32]; }
  else { src = wv + (o-64)*Cn; bs = bv[o-64]; }
  Wp[o*Cn+t] = f2bf(src[t]);
  if(t==0) bp[o] = bs;
}

#define AP 40
#define BP 264
#define GP 68

template<int GATED, int XBR>
__global__ __launch_bounds__(256) void k_gemm_qkv(
    const ushort_t* __restrict__ tb, const float* __restrict__ x,
    const ushort_t* __restrict__ XBp,
    const float* __restrict__ g1, const float* __restrict__ m2,
    const ushort_t* __restrict__ Wp, const float* __restrict__ bp,
    ushort_t* __restrict__ Yqk, ushort_t* __restrict__ Vb, int sel){
  __shared__ ushort_t SM[320*AP + 64*BP];
  __shared__ float gsh[256];
  ushort_t* Ws = SM;
  ushort_t* Bt = SM + 320*AP;
  int b = blockIdx.y;
  int n0 = blockIdx.x*64;
  int tid = threadIdx.x, lane = tid&63, wid = tid>>6;

  if(GATED){
    gsh[tid] = g1[b*Cn + tid];
    __syncthreads();
    float scl_n = (sel==1) ? m2[(size_t)b*Nn + n0 + (tid&63)] : 0.f;
    int cg = (tid>>6)*8;
#pragma unroll
    for(int p=0;p<8;p++){
      int c8 = p*32 + cg;
      float fv[8];
      if(XBR){
        const ushort_t* xb = XBp + (size_t)b*Cn*Nn + n0 + (tid&63);
#pragma unroll
        for(int k2=0;k2<8;k2++){
          float xf = bf2f(xb[(size_t)(c8+k2)*Nn]);
          fv[k2] = xf * (sel==0 ? gsh[c8+k2] : scl_n);
        }
      } else {
        const float* xb = x + (size_t)b*Cn*Nn + n0 + (tid&63);
#pragma unroll
        for(int k2=0;k2<8;k2++){
          float xf = xb[(size_t)(c8+k2)*Nn];
          fv[k2] = xf * (sel==0 ? gsh[c8+k2] : scl_n);
        }
      }
      uint4 pk;
      pk.x = (unsigned)f2bf(fv[0]) | ((unsigned)f2bf(fv[1])<<16);
      pk.y = (unsigned)f2bf(fv[2]) | ((unsigned)f2bf(fv[3])<<16);
      pk.z = (unsigned)f2bf(fv[4]) | ((unsigned)f2bf(fv[5])<<16);
      pk.w = (unsigned)f2bf(fv[6]) | ((unsigned)f2bf(fv[7])<<16);
      *(uint4*)&Bt[(tid&63)*BP + c8] = pk;
    }
  } else {
    const ushort_t* xb = tb + (size_t)b*Cn*Nn + n0 + (tid&63);
    int cg = (tid>>6)*8;
#pragma unroll
    for(int p=0;p<8;p++){
      int c8 = p*32 + cg;
      unsigned e0=xb[(size_t)(c8+0)*Nn], e1=xb[(size_t)(c8+1)*Nn];
      unsigned e2=xb[(size_t)(c8+2)*Nn], e3=xb[(size_t)(c8+3)*Nn];
      unsigned e4=xb[(size_t)(c8+4)*Nn], e5=xb[(size_t)(c8+5)*Nn];
      unsigned e6=xb[(size_t)(c8+6)*Nn], e7=xb[(size_t)(c8+7)*Nn];
      uint4 pk;
      pk.x = e0 | (e1<<16); pk.y = e2 | (e3<<16);
      pk.z = e4 | (e5<<16); pk.w = e6 | (e7<<16);
      *(uint4*)&Bt[(tid&63)*BP + c8] = pk;
    }
  }

  f32x4 acc[5][4];
#pragma unroll
  for(int f=0;f<5;f++)
#pragma unroll
    for(int g=0;g<4;g++) acc[f][g] = (f32x4){0.f,0.f,0.f,0.f};

  for(int ki=0;ki<8;ki++){
    __syncthreads();
#pragma unroll
    for(int q=0;q<5;q++){
      int fidx = q*256 + tid;
      int o = fidx>>2, kk = (fidx&3)*8;
      uint4 wv = *(const uint4*)&Wp[o*Cn + ki*32 + kk];
      *(uint4*)&Ws[o*AP + kk] = wv;
    }
    __syncthreads();
    bf8 bfr[4];
#pragma unroll
    for(int g=0;g<4;g++)
      bfr[g] = *(const bf8*)&Bt[(g*16 + (lane&15))*BP + ki*32 + (lane>>4)*8];
#pragma unroll
    for(int f=0;f<5;f++){
      bf8 a = *(const bf8*)&Ws[(wid*80 + f*16 + (lane&15))*AP + (lane>>4)*8];
#pragma unroll
      for(int g=0;g<4;g++) acc[f][g] = MFMA(a, bfr[g], acc[f][g]);
    }
  }

  __syncthreads();
#pragma unroll
  for(int f=0;f<5;f++){
    int o = wid*80 + f*16 + (lane>>4)*4;
#pragma unroll
    for(int i=0;i<4;i++){
      float bias = bp[o+i];
#pragma unroll
      for(int g=0;g<4;g++)
        SM[(o+i)*GP + g*16 + (lane&15)] = f2bf(acc[f][g][i] + bias);
    }
  }
  __syncthreads();
  for(int u=tid; u<320*8; u+=256){
    int lo_ = u>>3, c8 = (u&7)*8;
    ushort_t* dst = (lo_<64) ? (Yqk + ((size_t)b*64 + lo_)*Nn)
                             : (Vb + ((size_t)b*Cn + (lo_-64))*Nn);
    *(uint4*)&dst[n0 + c8] = *(uint4*)&SM[lo_*GP + c8];
  }
}

// per-plane 96x96 bf16 transpose (standalone, used for Y)
__global__ __launch_bounds__(256) void k_transpose_b(const ushort_t* __restrict__ src,
                                                     ushort_t* __restrict__ dst){
  __shared__ ushort_t Ls[96*98];
  size_t base = (size_t)blockIdx.x * Nn;
  int tid = threadIdx.x;
  for(int e=tid*2; e<Nn; e+=512){
    unsigned int u = *(const unsigned int*)&src[base+e];
    int r=e/96, c=e%96;
    *(unsigned int*)&Ls[r*98+c] = u;
  }
  __syncthreads();
  for(int e=tid*2; e<Nn; e+=512){
    int r=e/96, c=e%96;
    unsigned int u = (unsigned int)Ls[c*98+r] | (((unsigned int)Ls[(c+1)*98+r])<<16);
    *(unsigned int*)&dst[base+e] = u;
  }
}

// unified QK^T -> fp16 logits
__global__ __launch_bounds__(256) void k_e2(const ushort_t* __restrict__ Yqk,
    const ushort_t* __restrict__ Yqkt, ushort_t* __restrict__ attl,
    ushort_t* __restrict__ attr){
  __shared__ ushort_t Qt[96*AP];
  __shared__ ushort_t Kt[96*AP];
  int r = blockIdx.x, mode = blockIdx.y, b = blockIdx.z;
  const ushort_t* Y = mode ? Yqk : Yqkt;
  int pm   = mode ? 1  : 96;
  int pr   = mode ? 96 : 1;
  ushort_t* attx = mode ? attr : attl;
  int tid = threadIdx.x, lane = tid&63, wid = tid>>6;
  {
    int half = tid>>7;
    int cg   = (tid>>5)&3;
    int l32  = tid&31;
    ushort_t* T = half ? Kt : Qt;
    const ushort_t* S = Y + ((size_t)b*64 + half*32 + cg*8)*Nn + (size_t)r*96;
#pragma unroll
    for(int p=0;p<3;p++){
      int sp = p*32 + l32;
      unsigned e0=S[(size_t)0*Nn+sp], e1=S[(size_t)1*Nn+sp];
      unsigned e2=S[(size_t)2*Nn+sp], e3=S[(size_t)3*Nn+sp];
      unsigned e4=S[(size_t)4*Nn+sp], e5=S[(size_t)5*Nn+sp];
      unsigned e6=S[(size_t)6*Nn+sp], e7=S[(size_t)7*Nn+sp];
      uint4 pk;
      pk.x = e0 | (e1<<16); pk.y = e2 | (e3<<16);
      pk.z = e4 | (e5<<16); pk.w = e6 | (e7<<16);
      *(uint4*)&T[sp*AP + cg*8] = pk;
    }
  }
  __syncthreads();
  int mb = (wid>>1)*48, nb = (wid&1)*48;
  const f32x4 z4 = {0.f,0.f,0.f,0.f};
  f32x4 acc[3][3];
  bf8 a[3], bb[3];
#pragma unroll
  for(int f=0;f<3;f++) a[f] = *(const bf8*)&Qt[(mb+f*16+(lane&15))*AP + (lane>>4)*8];
#pragma unroll
  for(int g=0;g<3;g++) bb[g] = *(const bf8*)&Kt[(nb+g*16+(lane&15))*AP + (lane>>4)*8];
#pragma unroll
  for(int f=0;f<3;f++)
#pragma unroll
    for(int g=0;g<3;g++) acc[f][g] = MFMA(a[f], bb[g], z4);
#pragma unroll
  for(int f=0;f<3;f++)
#pragma unroll
    for(int i=0;i<4;i++){
      int m = mb + f*16 + (lane>>4)*4 + i;
      ushort_t* arow = attx + ((size_t)b*Nn + (size_t)m*pm + (size_t)r*pr)*96;
#pragma unroll
      for(int g=0;g<3;g++){
        int n = nb + g*16 + (lane&15);
        arow[n] = f2h(acc[f][g][i]);
      }
    }
}

// fused: softmax_ip (blocks x<1164) || per-plane V transpose (x>=1164)
__global__ __launch_bounds__(256) void k_smvt(ushort_t* attl, ushort_t* attr,
    const ushort_t* __restrict__ Vsrc, ushort_t* __restrict__ Vdst){
  __shared__ ushort_t Ls[96*98];
  int b = blockIdx.z;
  if(blockIdx.x < 1164){
    int wave = threadIdx.x>>6, l = threadIdx.x&63;
    int t = blockIdx.x*4 + wave;               // 0..4655
    int i=0, base=0;
    while(base + (96-i) <= t){ base += 96-i; i++; }
    int j = i + (t-base);
    int hf = l>>5, l32 = l&31;
    int h = hf ? j : i, w = hf ? i : j;
    size_t p = (size_t)b*Nn + (size_t)h*96 + w;
    const ushort_t* al = attl + p*96;
    const ushort_t* ar = attr + p*96;
    float v[6];
#pragma unroll
    for(int k=0;k<3;k++){
      int el = l32 + 32*k;
      float vv = h2f(al[el]);
      v[k] = (el==h) ? -1e30f : vv;
    }
#pragma unroll
    for(int k=0;k<3;k++) v[3+k] = h2f(ar[l32 + 32*k]);
    float mx = v[0];
#pragma unroll
    for(int k=1;k<6;k++) mx = fmaxf(mx, v[k]);
#pragma unroll
    for(int o=16;o;o>>=1) mx = fmaxf(mx, __shfl_xor(mx, o, 64));
    float e[6], s=0.f;
#pragma unroll
    for(int k=0;k<6;k++){ e[k]=expf(v[k]-mx); s+=e[k]; }
#pragma unroll
    for(int o=16;o;o>>=1) s += __shfl_xor(s, o, 64);
    float inv = 1.f/s;
    size_t q = (size_t)b*Nn + (size_t)w*96 + h;
    ushort_t* oh = attl + q*96;
    ushort_t* ow = attr + p*96;
#pragma unroll
    for(int k=0;k<3;k++) oh[l32+32*k] = f2bf(e[k]*inv);
#pragma unroll
    for(int k=0;k<3;k++) ow[l32+32*k] = f2bf(e[3+k]*inv);
  } else {
    int c = blockIdx.x - 1164;
    size_t base = ((size_t)b*Cn + c) * Nn;
    int tid = threadIdx.x;
    for(int e=tid*2; e<Nn; e+=512){
      unsigned int u = *(const unsigned int*)&Vsrc[base+e];
      int r=e/96, cc=e%96;
      *(unsigned int*)&Ls[r*98+cc] = u;
    }
    __syncthreads();
    for(int e=tid*2; e<Nn; e+=512){
      int r=e/96, cc=e%96;
      unsigned int u = (unsigned int)Ls[cc*98+r] | (((unsigned int)Ls[(cc+1)*98+r])<<16);
      *(unsigned int*)&Vdst[base+e] = u;
    }
  }
}

#define SP 104   // att staging pitch (2-way only, free)
#define RP 100   // repack pitch (64-row buffer)

// unified PV, 256 thr, 64 ch/block: blockIdx.y = mode*4 + quarter
// VGPR diet: acc[6] (24 regs), V fragment loaded per-j0 (1 live) -> target <=64 VGPR,
// 8 waves/SIMD; single-phase 64-row epilogue (exactly the repack tile).
template<int RES, int XBR>
__global__ __launch_bounds__(256) void k_pv2(const ushort_t* __restrict__ VB,
    const ushort_t* __restrict__ VTb, const ushort_t* __restrict__ attw,
    const ushort_t* __restrict__ atth, const float* __restrict__ x,
    const ushort_t* __restrict__ XBp,
    const float* __restrict__ g1, const float* __restrict__ m2,
    const ushort_t* __restrict__ residb, ushort_t* __restrict__ Tob,
    ushort_t* __restrict__ OTb, const float* __restrict__ gp, int sel){
  __shared__ ushort_t SMEM[96*SP];    // 19968B; repack 64*RP=12800B fits
  int r = blockIdx.x, mode = blockIdx.y>>2, q4 = blockIdx.y&3, b = blockIdx.z;
  float gm = gp[0];
  int tid = threadIdx.x, lane = tid&63, wid = tid>>6;
  const ushort_t* V = mode ? VTb : VB;
  size_t vbase = (size_t)b*Cn*Nn + (size_t)r*96;
  int cb = q4*64 + wid*16;            // this wave's 16-channel base
  const ushort_t* ab = (mode ? atth : attw) + ((size_t)b*Nn + (size_t)r*96)*96;
  for(int u=tid; u<96*12; u+=256){
    int n=u/12, j8=(u%12)*8;
    uint4 qv = *(const uint4*)&ab[n*96 + j8];
    *(uint4*)&SMEM[n*SP + j8] = qv;
  }
  __syncthreads();
  f32x4 acc[6];
#pragma unroll
  for(int g=0;g<6;g++) acc[g] = (f32x4){0.f,0.f,0.f,0.f};
#pragma unroll
  for(int j0=0;j0<3;j0++){
    bf8 vf = *(const bf8*)&V[vbase
        + (size_t)(cb + (lane&15))*Nn + j0*32 + (lane>>4)*8];
    bf8 bfr[6];
#pragma unroll
    for(int g=0;g<6;g++)
      bfr[g] = *(const bf8*)&SMEM[(g*16+(lane&15))*SP + j0*32 + (lane>>4)*8];
#pragma unroll
    for(int g=0;g<6;g++) acc[g] = MFMA(vf, bfr[g], acc[g]);
  }
  // single-phase epilogue: 64 rows (4 waves x 16), repack then coalesced IO
  __syncthreads();
  {
    int rl = wid*16 + (lane>>4)*4;   // local row base 0..63
#pragma unroll
    for(int i=0;i<4;i++)
#pragma unroll
      for(int g=0;g<6;g++)
        SMEM[(rl+i)*RP + g*16 + (lane&15)] = f2bf(gm*acc[g][i]);
  }
  __syncthreads();
  for(int u=tid; u<64*12; u+=256){
    int rl = u/12, q8 = (u%12)*8;
    int c = q4*64 + rl;
    size_t row = vbase + (size_t)c*Nn;
    uint4 v = *(uint4*)&SMEM[rl*RP + q8];
    if(mode){
      *(uint4*)&OTb[row + q8] = v;
    } else {
      unsigned* vp=(unsigned*)&v;
      float rs[8];
      if(RES==1){
        uint4 rv = *(const uint4*)&residb[row + q8];
        unsigned* rp=(unsigned*)&rv;
#pragma unroll
        for(int k=0;k<4;k++){
          rs[2*k]   = bf2f((ushort_t)(rp[k]&0xffff));
          rs[2*k+1] = bf2f((ushort_t)(rp[k]>>16));
        }
      } else {
        float xv[8];
        if(XBR){
          uint4 xq = *(const uint4*)&XBp[row + q8];
          unsigned* xp=(unsigned*)&xq;
#pragma unroll
          for(int k=0;k<4;k++){
            xv[2*k]   = bf2f((ushort_t)(xp[k]&0xffff));
            xv[2*k+1] = bf2f((ushort_t)(xp[k]>>16));
          }
        } else {
          float4 x1 = *(const float4*)&x[row + q8];
          float4 x2 = *(const float4*)&x[row + q8 + 4];
          xv[0]=x1.x; xv[1]=x1.y; xv[2]=x1.z; xv[3]=x1.w;
          xv[4]=x2.x; xv[5]=x2.y; xv[6]=x2.z; xv[7]=x2.w;
        }
        if(sel==0){
          float g = g1[b*Cn + c];
#pragma unroll
          for(int k=0;k<8;k++) rs[k] = xv[k]*g;
        } else {
          float4 m1 = *(const float4*)&m2[(size_t)b*Nn + (size_t)r*96 + q8];
          float4 m2v= *(const float4*)&m2[(size_t)b*Nn + (size_t)r*96 + q8 + 4];
          float mv[8] = {m1.x,m1.y,m1.z,m1.w,m2v.x,m2v.y,m2v.z,m2v.w};
#pragma unroll
          for(int k=0;k<8;k++) rs[k] = xv[k]*mv[k];
        }
      }
      uint4 o; unsigned* op=(unsigned*)&o;
#pragma unroll
      for(int k=0;k<4;k++){
        float lo = bf2f((ushort_t)(vp[k]&0xffff)) + rs[2*k];
        float hi = bf2f((ushort_t)(vp[k]>>16))    + rs[2*k+1];
        op[k] = (unsigned)f2bf(lo) | ((unsigned)f2bf(hi)<<16);
      }
      *(uint4*)&Tob[row + q8] = o;
    }
  }
}

// merge: VAR 0: outb += OT^T ; VAR 2: outb += add + OT^T ; VAR 4: outf = add + OT^T
template<int VAR>
__global__ __launch_bounds__(256) void k_merge(float* __restrict__ outf,
    ushort_t* __restrict__ outb, const ushort_t* __restrict__ add,
    const ushort_t* __restrict__ OT){
  __shared__ ushort_t Ls[96*98];
  size_t base = (size_t)blockIdx.x * Nn;
  int tid = threadIdx.x;
  for(int e=tid*2; e<Nn; e+=512){
    int r=e/96, c=e%96;
    *(unsigned int*)&Ls[r*98+c] = *(const unsigned int*)&OT[base+e];
  }
  __syncthreads();
  for(int e=tid*4; e<Nn; e+=1024){
    int r=e/96, c=e%96;
    float t0 = bf2f(Ls[(c+0)*98+r]), t1 = bf2f(Ls[(c+1)*98+r]);
    float t2 = bf2f(Ls[(c+2)*98+r]), t3 = bf2f(Ls[(c+3)*98+r]);
    if(VAR==4){
      uint2 v = *(const uint2*)&add[base+e];
      float4 o;
      o.x = bf2f((ushort_t)(v.x&0xffff)) + t0;
      o.y = bf2f((ushort_t)(v.x>>16))    + t1;
      o.z = bf2f((ushort_t)(v.y&0xffff)) + t2;
      o.w = bf2f((ushort_t)(v.y>>16))    + t3;
      *(float4*)&outf[base+e] = o;
    } else {
      uint2 u = *(uint2*)&outb[base+e];
      float a0 = bf2f((ushort_t)(u.x&0xffff)) + t0;
      float a1 = bf2f((ushort_t)(u.x>>16))    + t1;
      float a2 = bf2f((ushort_t)(u.y&0xffff)) + t2;
      float a3 = bf2f((ushort_t)(u.y>>16))    + t3;
      if(VAR==2){
        uint2 v = *(const uint2*)&add[base+e];
        a0 += bf2f((ushort_t)(v.x&0xffff));
        a1 += bf2f((ushort_t)(v.x>>16));
        a2 += bf2f((ushort_t)(v.y&0xffff));
        a3 += bf2f((ushort_t)(v.y>>16));
      }
      u.x = (unsigned)f2bf(a0) | ((unsigned)f2bf(a1)<<16);
      u.y = (unsigned)f2bf(a2) | ((unsigned)f2bf(a3)<<16);
      *(uint2*)&outb[base+e] = u;
    }
  }
}

extern "C" void kernel_launch(void* const* d_in, const int* in_sizes, int n_in,
                              void* d_out, int out_size, void* d_ws, size_t ws_size,
                              hipStream_t stream){
  const float* x    = (const float*)d_in[0];
  const float* wqr  = (const float*)d_in[1];
  const float* wvr  = (const float*)d_in[2];
  const float* wup  = (const float*)d_in[3];
  const float* bup  = (const float*)d_in[4];
  const float* wql  = (const float*)d_in[5];
  const float* wvl  = (const float*)d_in[6];
  const float* crwq = (const float*)d_in[7];
  const float* crbq = (const float*)d_in[8];
  const float* crwk = (const float*)d_in[9];
  const float* crbk = (const float*)d_in[10];
  const float* crwv = (const float*)d_in[11];
  const float* crbv = (const float*)d_in[12];
  const float* gma  = (const float*)d_in[13];
  float* out = (float*)d_out;

  char* wsb = (char*)d_ws;
  ushort_t* TT   = (ushort_t*)wsb; wsb += 2*XSZk*2;   // T1 | T2 (T2 also final staging)
  ushort_t* VB2  = (ushort_t*)wsb; wsb += XSZk*2;
  ushort_t* VT2  = (ushort_t*)wsb; wsb += XSZk*2;
  ushort_t* Y2   = (ushort_t*)wsb; wsb += YSZk*2;
  ushort_t* Yt2  = (ushort_t*)wsb; wsb += YSZk*2;
  ushort_t* ATTL = (ushort_t*)wsb; wsb += ATTSZ*2;
  ushort_t* ATTR = (ushort_t*)wsb; wsb += ATTSZ*2;
  float*    partp= (float*)wsb;    wsb += (size_t)16*Bn*Nn*4;
  ushort_t* Wpb  = (ushort_t*)wsb; wsb += 320*Cn*2;
  float*    bp   = (float*)wsb;    wsb += 320*4;
  float*    xmean= (float*)wsb;    wsb += Bn*Cn*4;
  float*    wvec = (float*)wsb;    wsb += Bn*Cn*4;
  float*    xw   = (float*)wsb;    wsb += Bn*Cn*4;
  float*    g1   = (float*)wsb;    wsb += Bn*Cn*4;
  float*    mraw = (float*)wsb;    wsb += (size_t)PIXn*4;
  float*    maskb= (float*)wsb;    wsb += (size_t)PIXn*4;
  float*    craw = (float*)wsb;    wsb += (size_t)PIXn*4;
  float*    m2   = (float*)wsb;    wsb += (size_t)PIXn*4;
  ushort_t* XB   = (ushort_t*)wsb;  // +75.5MB only if useXB
  const int useXB = (ws_size >= (size_t)484000000) ? 1 : 0;

  k_packb<<<320,256,0,stream>>>(crwq,crbq,crwk,crbk,crwv,crbv,Wpb,bp);

  // ---- gating reductions (gates fused downstream) ----
  if(useXB) k_pass1<1><<<dim3(16,Bn),1024,0,stream>>>(x, wqr, xmean, partp, XB);
  else      k_pass1<0><<<dim3(16,Bn),1024,0,stream>>>(x, wqr, xmean, partp, nullptr);
  k_red16<<<Bn*Nn/256,256,0,stream>>>(partp, mraw);
  k_sn1<<<32,1024,0,stream>>>(mraw, maskb, xmean, wql, wvl, wvec);
  if(useXB) k_pass2<1><<<dim3(16,Bn),1024,0,stream>>>(nullptr, XB, wvec, maskb, xw, partp);
  else      k_pass2<0><<<dim3(16,Bn),1024,0,stream>>>(x, nullptr, wvec, maskb, xw, partp);
  k_red16<<<Bn*Nn/256,256,0,stream>>>(partp, craw);
  k_sn2<<<32,1024,0,stream>>>(craw, m2, xw, wvr, wup, bup, g1);

  ushort_t* T2p = TT + XSZk;

  // gated cross for one sel: TT[sel] = gm*VA_w + x*gate ; VT2 = OT (pvh^T)
  auto crossg = [&](int sel){
    if(useXB) k_gemm_qkv<1,1><<<dim3(Nn/64,Bn),256,0,stream>>>(nullptr, nullptr, XB, g1, m2, Wpb, bp, Y2, VB2, sel);
    else      k_gemm_qkv<1,0><<<dim3(Nn/64,Bn),256,0,stream>>>(nullptr, x, nullptr, g1, m2, Wpb, bp, Y2, VB2, sel);
    k_transpose_b<<<Bn*64,256,0,stream>>>(Y2, Yt2);
    k_e2<<<dim3(96,2,Bn),256,0,stream>>>(Y2, Yt2, ATTL, ATTR);
    k_smvt<<<dim3(1164+256,1,Bn),256,0,stream>>>(ATTL, ATTR, VB2, VT2);  // softmax || V-transpose
    ushort_t* To = TT + (size_t)sel*XSZk;
    if(useXB) k_pv2<0,1><<<dim3(96,8,Bn),256,0,stream>>>(VB2, VT2, ATTR, ATTL, nullptr, XB, g1, m2, nullptr, To, VT2, gma, sel);
    else      k_pv2<0,0><<<dim3(96,8,Bn),256,0,stream>>>(VB2, VT2, ATTR, ATTL, x, nullptr, g1, m2, nullptr, To, VT2, gma, sel);
  };

  crossg(0);
  k_merge<0><<<Bn*Cn,256,0,stream>>>(nullptr, TT, nullptr, VT2);   // T1 += OT^T
  crossg(1);
  k_merge<2><<<Bn*Cn,256,0,stream>>>(nullptr, TT, T2p, VT2);       // T1 += T2 + OT^T

  // ---- final cross on T1 -> bf16 staging in T2 slot -> fp32 out ----
  k_gemm_qkv<0,0><<<dim3(Nn/64,Bn),256,0,stream>>>(TT, nullptr, nullptr, nullptr, nullptr, Wpb, bp, Y2, VB2, 0);
  k_transpose_b<<<Bn*64,256,0,stream>>>(Y2, Yt2);
  k_e2<<<dim3(96,2,Bn),256,0,stream>>>(Y2, Yt2, ATTL, ATTR);
  k_smvt<<<dim3(1164+256,1,Bn),256,0,stream>>>(ATTL, ATTR, VB2, VT2);
  k_pv2<1,0><<<dim3(96,8,Bn),256,0,stream>>>(VB2, VT2, ATTR, ATTL,
      nullptr, nullptr, nullptr, nullptr, /*residb=T1*/TT, /*To*/T2p, VT2, gma, 0);
  k_merge<4><<<Bn*Cn,256,0,stream>>>(out, nullptr, T2p, VT2);      // out = T2 + OT^T
}